// Round 9
// baseline (1024.962 us; speedup 1.0000x reference)
//
#include <hip/hip_runtime.h>
#include <cstddef>

#define N_NODES 16384
#define HD      512
#define INDIM   300
#define INP     320
#define NDEP    48
#define NLEAF   10923
#define NINT    5461
#define KT      32
#define LM      16
#define LCOL    128

typedef unsigned int u32;
typedef unsigned short u16;
typedef __attribute__((ext_vector_type(8))) short short8;
typedef __attribute__((ext_vector_type(4))) float f32x4;

typedef __attribute__((address_space(1))) const u32 as1_u32;
typedef __attribute__((address_space(3))) u32 as3_u32;

__device__ __forceinline__ float sigmoidf_(float v) {
    return 1.f / (1.f + __expf(-v));
}
__device__ __forceinline__ float tanhf_(float v) {
    v = fminf(15.f, fmaxf(-15.f, v));
    const float e = __expf(2.f * v);
    return (e - 1.f) / (e + 1.f);
}
__device__ __forceinline__ u16 f2bf(float f) {
    u32 u = __float_as_uint(f);
    u32 r = (u + 0x7fffu + ((u >> 16) & 1u)) >> 16;
    return (u16)r;
}
__device__ __forceinline__ float b2f(u16 v) {
    return __uint_as_float((u32)v << 16);
}
__device__ __forceinline__ u32 pack2(float a, float b) {
    return (u32)f2bf(a) | ((u32)f2bf(b) << 16);
}

// ---------------------------------------------------------------------------
// vectorized fp32->bf16 convert (rows 1200B = 75x16B => float4 clean)
// ---------------------------------------------------------------------------
#define RA  (N_NODES * 75)
#define RB  (N_NODES * 10)
#define RC1 (1536 * 75)
#define RC2 (1536 * 10)
#define RD  (1536 * 128)
#define CV_TOT (RA + RB + RC1 + RC2 + RD)

__global__ __launch_bounds__(256)
void convert_vec_kernel(const float* __restrict__ x,
                        const float* __restrict__ iux_w, const float* __restrict__ fx_w,
                        const float* __restrict__ iuh_w, const float* __restrict__ fh_w,
                        u16* __restrict__ xb, u16* __restrict__ WXb, u16* __restrict__ WHb)
{
    int idx = blockIdx.x * 256 + threadIdx.x;
    if (idx < RA) {
        const int r = idx / 75, k4 = idx - r * 75;
        const float4 v = *reinterpret_cast<const float4*>(x + (size_t)r * INDIM + k4 * 4);
        *reinterpret_cast<uint2*>(&xb[(size_t)r * INP + k4 * 4]) =
            make_uint2(pack2(v.x, v.y), pack2(v.z, v.w));
        return;
    }
    idx -= RA;
    if (idx < RB) {
        const int r = idx / 10, j = idx - r * 10;
        reinterpret_cast<u32*>(xb)[(size_t)r * 160 + 150 + j] = 0u;
        return;
    }
    idx -= RB;
    if (idx < RC1) {
        const int r = idx / 75, k4 = idx - r * 75;
        const float* src = (r < 1024) ? (iux_w + (size_t)r * INDIM)
                                      : (fx_w + (size_t)(r - 1024) * INDIM);
        const float4 v = *reinterpret_cast<const float4*>(src + k4 * 4);
        *reinterpret_cast<uint2*>(&WXb[(size_t)r * INP + k4 * 4]) =
            make_uint2(pack2(v.x, v.y), pack2(v.z, v.w));
        return;
    }
    idx -= RC1;
    if (idx < RC2) {
        const int r = idx / 10, j = idx - r * 10;
        reinterpret_cast<u32*>(WXb)[(size_t)r * 160 + 150 + j] = 0u;
        return;
    }
    idx -= RC2;
    {
        const int r = idx >> 7, k4 = idx & 127;
        const float* src = (r < 1024) ? (iuh_w + (size_t)r * HD)
                                      : (fh_w + (size_t)(r - 1024) * HD);
        const float4 v = *reinterpret_cast<const float4*>(src + k4 * 4);
        *reinterpret_cast<uint2*>(&WHb[(size_t)r * HD + k4 * 4]) =
            make_uint2(pack2(v.x, v.y), pack2(v.z, v.w));
    }
}

// ---------------------------------------------------------------------------
// bf16 MFMA GEMM body: C[M][N] (bf16) = A[M][K] @ B[N][K]^T
// 128x128 tile, BK=64, 4 waves (2x2), 16x16x32 MFMA, global_load_lds(16B),
// XOR chunk-swizzle. Requires K%64==0, N%128==0.
// ---------------------------------------------------------------------------
__device__ __forceinline__
void gemm_body(u16* As, u16* Bs,
               const u16* __restrict__ A, int lda,
               const u16* __restrict__ B, int ldb,
               u16* __restrict__ C, int ldc,
               int M, int K, int bx, int by)
{
    const int tid  = threadIdx.x;
    const int lane = tid & 63;
    const int wave = tid >> 6;
    const int mBlk = bx * 128;
    const int nBlk = by * 128;

    const int wr = (wave >> 1) * 64;
    const int wc = (wave & 1) * 64;
    const int fr = lane & 15;
    const int kg = lane >> 4;

    f32x4 acc[4][4];
    #pragma unroll
    for (int i = 0; i < 4; ++i)
        #pragma unroll
        for (int j = 0; j < 4; ++j) acc[i][j] = (f32x4){0.f, 0.f, 0.f, 0.f};

    int offA[4], offB[4];
    #pragma unroll
    for (int it = 0; it < 4; ++it) {
        const int s   = it * 256 + tid;
        const int row = s >> 3, c = s & 7;
        const int cs  = c ^ (row & 7);
        int ga = mBlk + row; if (ga > M - 1) ga = M - 1;
        offA[it] = ga * lda + cs * 8;
        offB[it] = (nBlk + row) * ldb + cs * 8;
    }

    for (int k0 = 0; k0 < K; k0 += 64) {
        #pragma unroll
        for (int it = 0; it < 4; ++it) {
            const int ldsOff = (it * 256 + wave * 64) * 8;
            __builtin_amdgcn_global_load_lds((as1_u32*)(A + offA[it] + k0),
                                             (as3_u32*)(&As[ldsOff]), 16, 0, 0);
            __builtin_amdgcn_global_load_lds((as1_u32*)(B + offB[it] + k0),
                                             (as3_u32*)(&Bs[ldsOff]), 16, 0, 0);
        }
        __syncthreads();
        #pragma unroll
        for (int half = 0; half < 2; ++half) {
            const int ckb = half * 4 + kg;
            short8 af[4], bf[4];
            #pragma unroll
            for (int f = 0; f < 4; ++f) {
                const int ar = wr + f * 16 + fr;
                af[f] = *(const short8*)&As[ar * 64 + ((ckb ^ (ar & 7)) * 8)];
                const int br = wc + f * 16 + fr;
                bf[f] = *(const short8*)&Bs[br * 64 + ((ckb ^ (br & 7)) * 8)];
            }
            #pragma unroll
            for (int mi = 0; mi < 4; ++mi)
                #pragma unroll
                for (int ni = 0; ni < 4; ++ni)
                    acc[mi][ni] = __builtin_amdgcn_mfma_f32_16x16x32_bf16(
                                      af[mi], bf[ni], acc[mi][ni], 0, 0, 0);
        }
        __syncthreads();
    }

    #pragma unroll
    for (int mi = 0; mi < 4; ++mi) {
        const int r0 = mBlk + wr + mi * 16 + kg * 4;
        #pragma unroll
        for (int v = 0; v < 4; ++v) {
            const int r = r0 + v;
            if (r >= M) continue;
            u16* crow = C + (size_t)r * ldc + nBlk + wc + fr;
            #pragma unroll
            for (int ni = 0; ni < 4; ++ni)
                crow[ni * 16] = f2bf(acc[mi][ni][v]);
        }
    }
}

// ---------------------------------------------------------------------------
// XP dual GEMM + emb projection + biases in ONE dispatch.
// ---------------------------------------------------------------------------
__global__ __launch_bounds__(256, 4)
void xp_gemm_emb_kernel(const u16* __restrict__ xb, const u16* __restrict__ WXb,
                        u16* __restrict__ XPiub, u16* __restrict__ XPfb,
                        int gx1, int n1, int gx2, int nG,
                        const float* __restrict__ demb,
                        const float* __restrict__ iue_w, const float* __restrict__ fe_w,
                        const float* __restrict__ iux_b, const float* __restrict__ iuh_b,
                        const float* __restrict__ iue_b, const float* __restrict__ fx_b,
                        const float* __restrict__ fh_b, const float* __restrict__ fe_b,
                        float* __restrict__ iemb, float* __restrict__ femb,
                        float* __restrict__ ibc, float* __restrict__ fbc)
{
    __shared__ u16 As[128 * 64];
    __shared__ u16 Bs[128 * 64];
    const int flat = blockIdx.x;
    if (flat < nG) {
        if (flat < n1) {
            gemm_body(As, Bs, xb, INP, WXb, INP, XPiub, 1024, N_NODES, INP,
                      flat % gx1, flat / gx1);
        } else {
            const int f2 = flat - n1;
            gemm_body(As, Bs, xb + (size_t)NLEAF * INP, INP,
                      WXb + (size_t)1024 * INP, INP, XPfb, 512, NINT, INP,
                      f2 % gx2, f2 / gx2);
        }
        return;
    }
    const int bo  = flat - nG;            // [0, 385)
    const int tid = threadIdx.x;
    if (bo == 384) {
        for (int o = tid; o < 1024; o += 256) ibc[o] = iux_b[o] + iuh_b[o] + iue_b[o];
        for (int o = tid; o < 512;  o += 256) fbc[o] = fx_b[o] + fh_b[o] + fe_b[o];
        return;
    }
    const int wave = tid >> 6;
    const int d    = tid & 63;
    const bool isI = (bo < 256);
    const int o    = (isI ? bo : bo - 256) * 4 + wave;
    if (d >= NDEP) return;
    const float* wrow = isI ? (iue_w + (size_t)o * HD) : (fe_w + (size_t)o * HD);
    const float* drow = demb + (size_t)d * HD;

    float4 a0 = make_float4(0.f, 0.f, 0.f, 0.f);
    float4 a1 = make_float4(0.f, 0.f, 0.f, 0.f);
    for (int k = 0; k < HD; k += 8) {
        const float4 wv0 = *reinterpret_cast<const float4*>(wrow + k);
        const float4 wv1 = *reinterpret_cast<const float4*>(wrow + k + 4);
        const float4 dv0 = *reinterpret_cast<const float4*>(drow + k);
        const float4 dv1 = *reinterpret_cast<const float4*>(drow + k + 4);
        a0.x = fmaf(dv0.x, wv0.x, a0.x); a0.y = fmaf(dv0.y, wv0.y, a0.y);
        a0.z = fmaf(dv0.z, wv0.z, a0.z); a0.w = fmaf(dv0.w, wv0.w, a0.w);
        a1.x = fmaf(dv1.x, wv1.x, a1.x); a1.y = fmaf(dv1.y, wv1.y, a1.y);
        a1.z = fmaf(dv1.z, wv1.z, a1.z); a1.w = fmaf(dv1.w, wv1.w, a1.w);
    }
    const float s = ((a0.x + a0.y) + (a0.z + a0.w)) + ((a1.x + a1.y) + (a1.z + a1.w));
    if (isI) iemb[(size_t)d * 1024 + o] = s;
    else     femb[(size_t)d * 512  + o] = s;
}

// Two GEMM jobs in one dispatch (flat 1-D grid split) — level loop.
__global__ __launch_bounds__(256, 4)
void gemm_bf16_dual_kernel(const u16* __restrict__ A1, int lda1,
                           const u16* __restrict__ B1, int ldb1,
                           u16* __restrict__ C1, int ldc1, int M1, int K1,
                           int gx1, int n1,
                           const u16* __restrict__ A2, int lda2,
                           const u16* __restrict__ B2, int ldb2,
                           u16* __restrict__ C2, int ldc2, int M2, int K2,
                           int gx2)
{
    __shared__ u16 As[128 * 64];
    __shared__ u16 Bs[128 * 64];
    const int flat = blockIdx.x;
    if (flat < n1) {
        gemm_body(As, Bs, A1, lda1, B1, ldb1, C1, ldc1, M1, K1,
                  flat % gx1, flat / gx1);
    } else {
        const int f2 = flat - n1;
        gemm_body(As, Bs, A2, lda2, B2, ldb2, C2, ldc2, M2, K2,
                  f2 % gx2, f2 / gx2);
    }
}

// ---------------------------------------------------------------------------
// fused leaf + hsum
// ---------------------------------------------------------------------------
__global__ __launch_bounds__(256)
void fused_leaf_kernel(const u16* __restrict__ XPiub,
                       const float* __restrict__ iemb, const float* __restrict__ ibc,
                       const int* __restrict__ cidx, const float* __restrict__ mh,
                       u16* __restrict__ Hb, u16* __restrict__ HSB, int loNext)
{
    const int g   = blockIdx.x;
    const int p   = loNext + g;
    const int j2  = threadIdx.x * 2;

    int ct[4]; float cm[4];
    #pragma unroll
    for (int c = 0; c < 4; ++c) { ct[c] = cidx[p * 4 + c]; cm[c] = mh[p * 4 + c]; }

    const float2 ibci = *reinterpret_cast<const float2*>(&ibc[j2]);
    const float2 ibcu = *reinterpret_cast<const float2*>(&ibc[512 + j2]);
    const float2 iei  = *reinterpret_cast<const float2*>(&iemb[j2]);
    const float2 ieu  = *reinterpret_cast<const float2*>(&iemb[512 + j2]);

    float hs0 = 0.f, hs1 = 0.f;
    #pragma unroll
    for (int c = 0; c < 4; ++c) {
        if (cm[c] == 0.f) continue;
        const int t = ct[c];
        const u32 xi = *reinterpret_cast<const u32*>(&XPiub[(size_t)t * 1024 + j2]);
        const u32 xu = *reinterpret_cast<const u32*>(&XPiub[(size_t)t * 1024 + 512 + j2]);
        const float h0 = tanhf_(sigmoidf_(b2f((u16)xi) + iei.x + ibci.x)
                                * tanhf_(b2f((u16)xu) + ieu.x + ibcu.x));
        const float h1 = tanhf_(sigmoidf_(b2f((u16)(xi >> 16)) + iei.y + ibci.y)
                                * tanhf_(b2f((u16)(xu >> 16)) + ieu.y + ibcu.y));
        *reinterpret_cast<u32*>(&Hb[(size_t)t * 512 + j2]) = pack2(h0, h1);
        hs0 += h0; hs1 += h1;
    }
    *reinterpret_cast<u32*>(&HSB[(size_t)g * 512 + j2]) = pack2(hs0, hs1);
}

// ---------------------------------------------------------------------------
// fused combine + hsum (used at l=1 and root). Child h from Hb (bf16).
// ---------------------------------------------------------------------------
__global__ __launch_bounds__(256)
void fused_combine_kernel(const u16* __restrict__ XPiub, const u16* __restrict__ XPfb,
                          const u16* __restrict__ PIUb, const u16* __restrict__ GFb,
                          const int* __restrict__ cidx, const int* __restrict__ cdep,
                          const float* __restrict__ mh, const float* __restrict__ me,
                          const float* __restrict__ iemb, const float* __restrict__ femb,
                          const float* __restrict__ ibc, const float* __restrict__ fbc,
                          u16* __restrict__ Hb, u16* __restrict__ HSB,
                          int lo, int loNext, int isRoot, float* __restrict__ outp)
{
    const int j2 = threadIdx.x * 2;

    int ct[4]; float cm[4];
    if (isRoot) {
        ct[0] = N_NODES - 1; cm[0] = 1.f;
        ct[1] = ct[2] = ct[3] = 0; cm[1] = cm[2] = cm[3] = 0.f;
    } else {
        const int p = loNext + blockIdx.x;
        #pragma unroll
        for (int c = 0; c < 4; ++c) { ct[c] = cidx[p * 4 + c]; cm[c] = mh[p * 4 + c]; }
    }

    const float2 ibci = *reinterpret_cast<const float2*>(&ibc[j2]);
    const float2 ibcu = *reinterpret_cast<const float2*>(&ibc[512 + j2]);
    const float2 fbc2 = *reinterpret_cast<const float2*>(&fbc[j2]);

    float hs0 = 0.f, hs1 = 0.f;
    #pragma unroll
    for (int c = 0; c < 4; ++c) {
        if (cm[c] == 0.f) continue;
        const int t = ct[c];

        int ci2[4], dp2[4]; float m2[4], e2[4];
        #pragma unroll
        for (int k = 0; k < 4; ++k) {
            ci2[k] = cidx[t * 4 + k]; dp2[k] = cdep[t * 4 + k];
            m2[k]  = mh[t * 4 + k];   e2[k]  = me[t * 4 + k];
        }

        float ei0 = 0.f, ei1 = 0.f, eu0 = 0.f, eu1 = 0.f;
        #pragma unroll
        for (int k = 0; k < 4; ++k) {
            if (e2[k] != 0.f) {
                const float* ie = iemb + (size_t)dp2[k] * 1024;
                const float2 a = *reinterpret_cast<const float2*>(&ie[j2]);
                const float2 b = *reinterpret_cast<const float2*>(&ie[512 + j2]);
                ei0 = fmaf(e2[k], a.x, ei0); ei1 = fmaf(e2[k], a.y, ei1);
                eu0 = fmaf(e2[k], b.x, eu0); eu1 = fmaf(e2[k], b.y, eu1);
            }
        }

        const u32 xi = *reinterpret_cast<const u32*>(&XPiub[(size_t)t * 1024 + j2]);
        const u32 xu = *reinterpret_cast<const u32*>(&XPiub[(size_t)t * 1024 + 512 + j2]);
        const u32 pi = *reinterpret_cast<const u32*>(&PIUb[(size_t)(t - lo) * 1024 + j2]);
        const u32 pu = *reinterpret_cast<const u32*>(&PIUb[(size_t)(t - lo) * 1024 + 512 + j2]);
        const u32 xf = *reinterpret_cast<const u32*>(&XPfb[(size_t)(t - NLEAF) * 512 + j2]);

        const float iu_i0 = b2f((u16)xi) + b2f((u16)pi) + ibci.x + ei0;
        const float iu_i1 = b2f((u16)(xi >> 16)) + b2f((u16)(pi >> 16)) + ibci.y + ei1;
        const float iu_u0 = b2f((u16)xu) + b2f((u16)pu) + ibcu.x + eu0;
        const float iu_u1 = b2f((u16)(xu >> 16)) + b2f((u16)(pu >> 16)) + ibcu.y + eu1;
        const float xf0 = b2f((u16)xf) + fbc2.x;
        const float xf1 = b2f((u16)(xf >> 16)) + fbc2.y;

        float fcs0 = 0.f, fcs1 = 0.f;
        #pragma unroll
        for (int k = 0; k < 4; ++k) {
            if (m2[k] != 0.f) {
                const u32 gf = *reinterpret_cast<const u32*>(&GFb[(size_t)ci2[k] * 512 + j2]);
                const u32 hb = *reinterpret_cast<const u32*>(&Hb[(size_t)ci2[k] * 512 + j2]);
                const float2 fe = *reinterpret_cast<const float2*>(&femb[(size_t)dp2[k] * 512 + j2]);
                const float fv0 = b2f((u16)gf) + xf0 + fe.x;
                const float fv1 = b2f((u16)(gf >> 16)) + xf1 + fe.y;
                fcs0 = fmaf(sigmoidf_(fv0), m2[k] * b2f((u16)hb), fcs0);
                fcs1 = fmaf(sigmoidf_(fv1), m2[k] * b2f((u16)(hb >> 16)), fcs1);
            }
        }

        const float h0 = tanhf_(fmaf(sigmoidf_(iu_i0), tanhf_(iu_u0), fcs0));
        const float h1 = tanhf_(fmaf(sigmoidf_(iu_i1), tanhf_(iu_u1), fcs1));
        *reinterpret_cast<u32*>(&Hb[(size_t)t * 512 + j2]) = pack2(h0, h1);
        hs0 += h0; hs1 += h1;
        if (isRoot) *reinterpret_cast<float2*>(&outp[j2]) = make_float2(h0, h1);
    }
    if (!isRoot)
        *reinterpret_cast<u32*>(&HSB[(size_t)blockIdx.x * 512 + j2]) = pack2(hs0, hs1);
}

// ---------------------------------------------------------------------------
// FCP: fused combine + inline projections for small levels (l >= 2).
// Block owns parent p = loNext+g (level l+1):
//  phase 1: combine math for <=4 level-l children -> h rows in LDS, Hb write
//  phase 2: GF[child]  = h[child] @ fh_w^T   (f32, for next level's combine)
//           PIU[p]     = hsum     @ iuh_w^T  (f32, for next level's combine)
// GF/Hb row sets are level-disjoint across dispatches; PIU ping-pongs.
// ---------------------------------------------------------------------------
__global__ __launch_bounds__(256)
void fcp_kernel(const u16* __restrict__ XPiub, const u16* __restrict__ XPfb,
                const u16* __restrict__ PIUin, u16* __restrict__ GFb,
                const int* __restrict__ cidx, const int* __restrict__ cdep,
                const float* __restrict__ mh, const float* __restrict__ me,
                const float* __restrict__ iemb, const float* __restrict__ femb,
                const float* __restrict__ ibc, const float* __restrict__ fbc,
                u16* __restrict__ Hb,
                const float* __restrict__ iuh_w, const float* __restrict__ fh_w,
                u16* __restrict__ PIUout, int lo, int loNext)
{
    __shared__ float hrow[4][512];
    __shared__ float hsum[512];
    const int j2 = threadIdx.x * 2;
    const int p  = loNext + blockIdx.x;

    int ct[4]; float cm[4];
    #pragma unroll
    for (int c = 0; c < 4; ++c) { ct[c] = cidx[p * 4 + c]; cm[c] = mh[p * 4 + c]; }

    const float2 ibci = *reinterpret_cast<const float2*>(&ibc[j2]);
    const float2 ibcu = *reinterpret_cast<const float2*>(&ibc[512 + j2]);
    const float2 fbc2 = *reinterpret_cast<const float2*>(&fbc[j2]);

    float hs0 = 0.f, hs1 = 0.f;
    #pragma unroll
    for (int c = 0; c < 4; ++c) {
        if (cm[c] == 0.f) { hrow[c][j2] = 0.f; hrow[c][j2 + 1] = 0.f; continue; }
        const int t = ct[c];

        int ci2[4], dp2[4]; float m2[4], e2[4];
        #pragma unroll
        for (int k = 0; k < 4; ++k) {
            ci2[k] = cidx[t * 4 + k]; dp2[k] = cdep[t * 4 + k];
            m2[k]  = mh[t * 4 + k];   e2[k]  = me[t * 4 + k];
        }

        float ei0 = 0.f, ei1 = 0.f, eu0 = 0.f, eu1 = 0.f;
        #pragma unroll
        for (int k = 0; k < 4; ++k) {
            if (e2[k] != 0.f) {
                const float* ie = iemb + (size_t)dp2[k] * 1024;
                const float2 a = *reinterpret_cast<const float2*>(&ie[j2]);
                const float2 b = *reinterpret_cast<const float2*>(&ie[512 + j2]);
                ei0 = fmaf(e2[k], a.x, ei0); ei1 = fmaf(e2[k], a.y, ei1);
                eu0 = fmaf(e2[k], b.x, eu0); eu1 = fmaf(e2[k], b.y, eu1);
            }
        }

        const u32 xi = *reinterpret_cast<const u32*>(&XPiub[(size_t)t * 1024 + j2]);
        const u32 xu = *reinterpret_cast<const u32*>(&XPiub[(size_t)t * 1024 + 512 + j2]);
        const u32 pi = *reinterpret_cast<const u32*>(&PIUin[(size_t)(t - lo) * 1024 + j2]);
        const u32 pu = *reinterpret_cast<const u32*>(&PIUin[(size_t)(t - lo) * 1024 + 512 + j2]);
        const u32 xf = *reinterpret_cast<const u32*>(&XPfb[(size_t)(t - NLEAF) * 512 + j2]);

        const float iu_i0 = b2f((u16)xi) + b2f((u16)pi) + ibci.x + ei0;
        const float iu_i1 = b2f((u16)(xi >> 16)) + b2f((u16)(pi >> 16)) + ibci.y + ei1;
        const float iu_u0 = b2f((u16)xu) + b2f((u16)pu) + ibcu.x + eu0;
        const float iu_u1 = b2f((u16)(xu >> 16)) + b2f((u16)(pu >> 16)) + ibcu.y + eu1;
        const float xf0 = b2f((u16)xf) + fbc2.x;
        const float xf1 = b2f((u16)(xf >> 16)) + fbc2.y;

        float fcs0 = 0.f, fcs1 = 0.f;
        #pragma unroll
        for (int k = 0; k < 4; ++k) {
            if (m2[k] != 0.f) {
                const u32 gf = *reinterpret_cast<const u32*>(&GFb[(size_t)ci2[k] * 512 + j2]);
                const u32 hb = *reinterpret_cast<const u32*>(&Hb[(size_t)ci2[k] * 512 + j2]);
                const float2 fe = *reinterpret_cast<const float2*>(&femb[(size_t)dp2[k] * 512 + j2]);
                const float fv0 = b2f((u16)gf) + xf0 + fe.x;
                const float fv1 = b2f((u16)(gf >> 16)) + xf1 + fe.y;
                fcs0 = fmaf(sigmoidf_(fv0), m2[k] * b2f((u16)hb), fcs0);
                fcs1 = fmaf(sigmoidf_(fv1), m2[k] * b2f((u16)(hb >> 16)), fcs1);
            }
        }

        const float h0 = tanhf_(fmaf(sigmoidf_(iu_i0), tanhf_(iu_u0), fcs0));
        const float h1 = tanhf_(fmaf(sigmoidf_(iu_i1), tanhf_(iu_u1), fcs1));
        *reinterpret_cast<u32*>(&Hb[(size_t)t * 512 + j2]) = pack2(h0, h1);
        hrow[c][j2] = h0; hrow[c][j2 + 1] = h1;
        hs0 += h0; hs1 += h1;
    }
    hsum[j2] = hs0; hsum[j2 + 1] = hs1;
    __syncthreads();

    // --- GF projection: wave-uniform child c, 8 output cols per thread ---
    {
        const int c  = threadIdx.x >> 6;
        const int jb = (threadIdx.x & 63) * 8;
        if (cm[c] != 0.f) {
            const int t = ct[c];
            #pragma unroll
            for (int jj = 0; jj < 8; ++jj) {
                const int j = jb + jj;
                const float* wrow = fh_w + (size_t)j * HD;
                float a0 = 0.f, a1 = 0.f, a2 = 0.f, a3 = 0.f;
                for (int k = 0; k < HD; k += 4) {
                    const float4 wv = *reinterpret_cast<const float4*>(wrow + k);
                    const float4 hv = *reinterpret_cast<const float4*>(&hrow[c][k]);
                    a0 = fmaf(hv.x, wv.x, a0); a1 = fmaf(hv.y, wv.y, a1);
                    a2 = fmaf(hv.z, wv.z, a2); a3 = fmaf(hv.w, wv.w, a3);
                }
                GFb[(size_t)t * 512 + j] = f2bf((a0 + a1) + (a2 + a3));
            }
        }
    }
    // --- PIU projection for parent p: 4 output cols per thread ---
    {
        #pragma unroll
        for (int jj = 0; jj < 4; ++jj) {
            const int j = threadIdx.x * 4 + jj;
            const float* wrow = iuh_w + (size_t)j * HD;
            float a0 = 0.f, a1 = 0.f, a2 = 0.f, a3 = 0.f;
            for (int k = 0; k < HD; k += 4) {
                const float4 wv = *reinterpret_cast<const float4*>(wrow + k);
                const float4 hv = *reinterpret_cast<const float4*>(&hsum[k]);
                a0 = fmaf(hv.x, wv.x, a0); a1 = fmaf(hv.y, wv.y, a1);
                a2 = fmaf(hv.z, wv.z, a2); a3 = fmaf(hv.w, wv.w, a3);
            }
            PIUout[(size_t)blockIdx.x * 1024 + j] = f2bf((a0 + a1) + (a2 + a3));
        }
    }
}

// ===========================================================================
// FALLBACK (round-1 fused fp32 path, needs only ~34 MB ws)
// ===========================================================================
__global__ __launch_bounds__(256)
void emb_setup_kernel(const float* __restrict__ demb,
                      const float* __restrict__ iue_w,
                      const float* __restrict__ fe_w,
                      const float* __restrict__ iux_b,
                      const float* __restrict__ iuh_b,
                      const float* __restrict__ iue_b,
                      const float* __restrict__ fx_b,
                      const float* __restrict__ fh_b,
                      const float* __restrict__ fe_b,
                      float* __restrict__ iemb,
                      float* __restrict__ femb,
                      float* __restrict__ ibc,
                      float* __restrict__ fbc)
{
    const int d   = blockIdx.x;
    const int tid = threadIdx.x;
    __shared__ float sd[HD];
    sd[tid]       = demb[d * HD + tid];
    sd[tid + 256] = demb[d * HD + 256 + tid];
    __syncthreads();

    #pragma unroll
    for (int r = 0; r < 4; ++r) {
        const int o = r * 256 + tid;
        const float* w = iue_w + (size_t)o * HD;
        float acc = 0.f;
        for (int k = 0; k < HD; k += 4) {
            const float4 wv = *reinterpret_cast<const float4*>(w + k);
            acc += sd[k] * wv.x + sd[k + 1] * wv.y + sd[k + 2] * wv.z + sd[k + 3] * wv.w;
        }
        iemb[(size_t)d * 1024 + o] = acc;
    }
    #pragma unroll
    for (int r = 0; r < 2; ++r) {
        const int o = r * 256 + tid;
        const float* w = fe_w + (size_t)o * HD;
        float acc = 0.f;
        for (int k = 0; k < HD; k += 4) {
            const float4 wv = *reinterpret_cast<const float4*>(w + k);
            acc += sd[k] * wv.x + sd[k + 1] * wv.y + sd[k + 2] * wv.z + sd[k + 3] * wv.w;
        }
        femb[(size_t)d * HD + o] = acc;
    }
    if (d == 0) {
        #pragma unroll
        for (int r = 0; r < 4; ++r) { const int o = r * 256 + tid; ibc[o] = iux_b[o] + iuh_b[o] + iue_b[o]; }
        #pragma unroll
        for (int r = 0; r < 2; ++r) { const int o = r * 256 + tid; fbc[o] = fx_b[o] + fh_b[o] + fe_b[o]; }
    }
}

__global__ __launch_bounds__(256, 2)
void level_kernel(const float* __restrict__ x,
                  const int*   __restrict__ child_idx,
                  const int*   __restrict__ child_dep,
                  const float* __restrict__ mask_h,
                  const float* __restrict__ mask_e,
                  const float* __restrict__ iux_w,
                  const float* __restrict__ iuh_w,
                  const float* __restrict__ fx_w,
                  const float* __restrict__ fh_w,
                  const float* __restrict__ iemb,
                  const float* __restrict__ femb,
                  const float* __restrict__ ibc,
                  const float* __restrict__ fbc,
                  float* __restrict__ H,
                  int tLo, int tEnd)
{
    __shared__ __align__(16) float sA[KT][68];
    __shared__ float sWI[KT][LCOL + 1];
    __shared__ float sWU[KT][LCOL + 1];
    __shared__ float sWF[KT][LCOL + 1];
    __shared__ int   sCidx[LM][4];
    __shared__ float sMh[LM][4];
    __shared__ int   sDep[LM][4];
    __shared__ float sMe[LM][4];

    const int tid  = threadIdx.x;
    const int base = tLo + blockIdx.x * LM;
    const int j0   = blockIdx.y * LCOL;

    if (tid < LM * 4) {
        const int m = tid >> 2, c = tid & 3;
        const int t = base + m;
        const bool v = (t < tEnd);
        sCidx[m][c] = v ? child_idx[t * 4 + c] : 0;
        sMh[m][c]   = v ? mask_h[t * 4 + c]    : 0.f;
        sDep[m][c]  = v ? child_dep[t * 4 + c] : 0;
        sMe[m][c]   = v ? mask_e[t * 4 + c]    : 0.f;
    }

    const int jj = tid & 63;
    const int mg = tid >> 6;

    float acc_i[4][2], acc_u[4][2], acc_fx[4][2], acc_f[4][2][4];
    #pragma unroll
    for (int mm = 0; mm < 4; ++mm)
        #pragma unroll
        for (int c2 = 0; c2 < 2; ++c2) {
            acc_i[mm][c2] = 0.f; acc_u[mm][c2] = 0.f; acc_fx[mm][c2] = 0.f;
            #pragma unroll
            for (int c = 0; c < 4; ++c) acc_f[mm][c2][c] = 0.f;
        }

    __syncthreads();

    for (int k0 = 0; k0 < HD; k0 += KT) {
        #pragma unroll
        for (int it = 0; it < 2; ++it) {
            const int chunk = tid + it * 256;
            const int mc = chunk >> 3;
            const int kk = (chunk & 7) * 4;
            const int m = mc >> 2, c = mc & 3;
            const float mhv = sMh[m][c];
            float4 v = make_float4(0.f, 0.f, 0.f, 0.f);
            if (mhv != 0.f)
                v = *reinterpret_cast<const float4*>(H + (size_t)sCidx[m][c] * HD + k0 + kk);
            sA[kk + 0][mc] = v.x; sA[kk + 1][mc] = v.y; sA[kk + 2][mc] = v.z; sA[kk + 3][mc] = v.w;
        }
        #pragma unroll
        for (int it = 0; it < 4; ++it) {
            const int chunk = tid + it * 256;
            const int row = chunk >> 3;
            const int kk = (chunk & 7) * 4;
            const float4 vI = *reinterpret_cast<const float4*>(iuh_w + (size_t)(j0 + row) * HD + k0 + kk);
            const float4 vU = *reinterpret_cast<const float4*>(iuh_w + (size_t)(j0 + row + 512) * HD + k0 + kk);
            const float4 vF = *reinterpret_cast<const float4*>(fh_w  + (size_t)(j0 + row) * HD + k0 + kk);
            sWI[kk + 0][row] = vI.x; sWI[kk + 1][row] = vI.y; sWI[kk + 2][row] = vI.z; sWI[kk + 3][row] = vI.w;
            sWU[kk + 0][row] = vU.x; sWU[kk + 1][row] = vU.y; sWU[kk + 2][row] = vU.z; sWU[kk + 3][row] = vU.w;
            sWF[kk + 0][row] = vF.x; sWF[kk + 1][row] = vF.y; sWF[kk + 2][row] = vF.z; sWF[kk + 3][row] = vF.w;
        }
        __syncthreads();
        #pragma unroll 4
        for (int k = 0; k < KT; ++k) {
            const float wi0 = sWI[k][jj], wi1 = sWI[k][jj + 64];
            const float wu0 = sWU[k][jj], wu1 = sWU[k][jj + 64];
            const float wf0 = sWF[k][jj], wf1 = sWF[k][jj + 64];
            #pragma unroll
            for (int mm = 0; mm < 4; ++mm) {
                const int m = mg + mm * 4;
                const float4 cv = *reinterpret_cast<const float4*>(&sA[k][m * 4]);
                const float hs = (cv.x + cv.y) + (cv.z + cv.w);
                acc_i[mm][0] = fmaf(hs, wi0, acc_i[mm][0]);
                acc_i[mm][1] = fmaf(hs, wi1, acc_i[mm][1]);
                acc_u[mm][0] = fmaf(hs, wu0, acc_u[mm][0]);
                acc_u[mm][1] = fmaf(hs, wu1, acc_u[mm][1]);
                acc_f[mm][0][0] = fmaf(cv.x, wf0, acc_f[mm][0][0]);
                acc_f[mm][1][0] = fmaf(cv.x, wf1, acc_f[mm][1][0]);
                acc_f[mm][0][1] = fmaf(cv.y, wf0, acc_f[mm][0][1]);
                acc_f[mm][1][1] = fmaf(cv.y, wf1, acc_f[mm][1][1]);
                acc_f[mm][0][2] = fmaf(cv.z, wf0, acc_f[mm][0][2]);
                acc_f[mm][1][2] = fmaf(cv.z, wf1, acc_f[mm][1][2]);
                acc_f[mm][0][3] = fmaf(cv.w, wf0, acc_f[mm][0][3]);
                acc_f[mm][1][3] = fmaf(cv.w, wf1, acc_f[mm][1][3]);
            }
        }
        __syncthreads();
    }

    for (int k0 = 0; k0 < INDIM; k0 += KT) {
        if (tid < 128) {
            const int m = tid >> 3;
            const int kk = (tid & 7) * 4;
            const int t = base + m;
            float4 v = make_float4(0.f, 0.f, 0.f, 0.f);
            if (t < tEnd && (k0 + kk + 3) < INDIM)
                v = *reinterpret_cast<const float4*>(x + (size_t)t * INDIM + k0 + kk);
            sA[kk + 0][m] = v.x; sA[kk + 1][m] = v.y; sA[kk + 2][m] = v.z; sA[kk + 3][m] = v.w;
        }
        #pragma unroll
        for (int it = 0; it < 4; ++it) {
            const int chunk = tid + it * 256;
            const int row = chunk >> 3;
            const int kk = (chunk & 7) * 4;
            float4 vI = make_float4(0.f, 0.f, 0.f, 0.f), vU = vI, vF = vI;
            if ((k0 + kk + 3) < INDIM) {
                vI = *reinterpret_cast<const float4*>(iux_w + (size_t)(j0 + row) * INDIM + k0 + kk);
                vU = *reinterpret_cast<const float4*>(iux_w + (size_t)(j0 + row + 512) * INDIM + k0 + kk);
                vF = *reinterpret_cast<const float4*>(fx_w  + (size_t)(j0 + row) * INDIM + k0 + kk);
            }
            sWI[kk + 0][row] = vI.x; sWI[kk + 1][row] = vI.y; sWI[kk + 2][row] = vI.z; sWI[kk + 3][row] = vI.w;
            sWU[kk + 0][row] = vU.x; sWU[kk + 1][row] = vU.y; sWU[kk + 2][row] = vU.z; sWU[kk + 3][row] = vU.w;
            sWF[kk + 0][row] = vF.x; sWF[kk + 1][row] = vF.y; sWF[kk + 2][row] = vF.z; sWF[kk + 3][row] = vF.w;
        }
        __syncthreads();
        #pragma unroll 4
        for (int k = 0; k < KT; ++k) {
            const float wi0 = sWI[k][jj], wi1 = sWI[k][jj + 64];
            const float wu0 = sWU[k][jj], wu1 = sWU[k][jj + 64];
            const float wf0 = sWF[k][jj], wf1 = sWF[k][jj + 64];
            #pragma unroll
            for (int mm = 0; mm < 4; ++mm) {
                const float xv = sA[k][mg + mm * 4];
                acc_i[mm][0]  = fmaf(xv, wi0, acc_i[mm][0]);
                acc_i[mm][1]  = fmaf(xv, wi1, acc_i[mm][1]);
                acc_u[mm][0]  = fmaf(xv, wu0, acc_u[mm][0]);
                acc_u[mm][1]  = fmaf(xv, wu1, acc_u[mm][1]);
                acc_fx[mm][0] = fmaf(xv, wf0, acc_fx[mm][0]);
                acc_fx[mm][1] = fmaf(xv, wf1, acc_fx[mm][1]);
            }
        }
        __syncthreads();
    }

    #pragma unroll
    for (int mm = 0; mm < 4; ++mm) {
        const int m = mg + mm * 4;
        const int t = base + m;
        if (t >= tEnd) continue;
        #pragma unroll
        for (int c2 = 0; c2 < 2; ++c2) {
            const int j = j0 + c2 * 64 + jj;
            float emb_i = 0.f, emb_u = 0.f;
            #pragma unroll
            for (int c = 0; c < 4; ++c) {
                const float mev = sMe[m][c];
                if (mev != 0.f) {
                    const float* ie = iemb + (size_t)sDep[m][c] * 1024;
                    emb_i = fmaf(mev, ie[j], emb_i);
                    emb_u = fmaf(mev, ie[j + 512], emb_u);
                }
            }
            const float iu_i = acc_i[mm][c2] + ibc[j] + emb_i;
            const float iu_u = acc_u[mm][c2] + ibc[j + 512] + emb_u;
            const float ig = sigmoidf_(iu_i);
            const float uu = tanhf_(iu_u);
            float fcs = 0.f;
            #pragma unroll
            for (int c = 0; c < 4; ++c) {
                const float mhv = sMh[m][c];
                if (mhv != 0.f) {
                    const float fv = acc_f[mm][c2][c] + acc_fx[mm][c2] + fbc[j]
                                   + femb[(size_t)sDep[m][c] * HD + j];
                    const float fg = sigmoidf_(fv);
                    const float chj = H[(size_t)sCidx[m][c] * HD + j] * mhv;
                    fcs = fmaf(fg, chj, fcs);
                }
            }
            H[(size_t)t * HD + j] = tanhf_(fmaf(ig, uu, fcs));
        }
    }
}

__global__ void copy_out_kernel(const float* __restrict__ H, float* __restrict__ out) {
    const int j = blockIdx.x * 256 + threadIdx.x;
    if (j < HD) out[j] = H[(size_t)(N_NODES - 1) * HD + j];
}

// ---------------------------------------------------------------------------
static const int lvlLo[9] = {0, 10923, 15019, 16043, 16299, 16363, 16379, 16383, 16384};
static const int lvlN[8]  = {10923, 4096, 1024, 256, 64, 16, 4, 1};

extern "C" void kernel_launch(void* const* d_in, const int* in_sizes, int n_in,
                              void* d_out, int out_size, void* d_ws, size_t ws_size,
                              hipStream_t stream)
{
    const float* x     = (const float*)d_in[0];
    const int*   cidx  = (const int*)  d_in[1];
    const int*   cdep  = (const int*)  d_in[2];
    const float* mh    = (const float*)d_in[3];
    const float* me    = (const float*)d_in[4];
    const float* demb  = (const float*)d_in[5];
    const float* iux_w = (const float*)d_in[6];
    const float* iux_b = (const float*)d_in[7];
    const float* iuh_w = (const float*)d_in[8];
    const float* iuh_b = (const float*)d_in[9];
    const float* iue_w = (const float*)d_in[10];
    const float* iue_b = (const float*)d_in[11];
    const float* fx_w  = (const float*)d_in[12];
    const float* fx_b  = (const float*)d_in[13];
    const float* fh_w  = (const float*)d_in[14];
    const float* fh_b  = (const float*)d_in[15];
    const float* fe_w  = (const float*)d_in[16];
    const float* fe_b  = (const float*)d_in[17];

    // ---- fast-path workspace layout (bytes) ----
    const size_t szHb   = (size_t)N_NODES * HD * 2;
    const size_t szXPi  = (size_t)N_NODES * 1024 * 2;
    const size_t szXPf  = (size_t)NINT * 512 * 2;
    const size_t szGF   = (size_t)N_NODES * HD * 2;
    const size_t szPIU  = (size_t)4096 * 1024 * 2;
    const size_t szPIU2 = (size_t)4096 * 1024 * 2;
    const size_t szHSB  = (size_t)4096 * 512 * 2;
    const size_t szXB   = (size_t)N_NODES * INP * 2;
    const size_t szWX   = (size_t)1536 * INP * 2;
    const size_t szWH   = (size_t)1536 * HD * 2;
    const size_t szIE   = (size_t)NDEP * 1024 * 4;
    const size_t szFE   = (size_t)NDEP * 512 * 4;
    const size_t szIB   = 4096, szFB = 2048;
    const size_t need = szHb + szXPi + szXPf + szGF + szPIU + szPIU2 + szHSB
                      + szXB + szWX + szWH + szIE + szFE + szIB + szFB;

    if (ws_size >= need) {
        char* w = (char*)d_ws;
        u16*   Hb    = (u16*)w;    w += szHb;
        u16*   XPiub = (u16*)w;    w += szXPi;
        u16*   XPfb  = (u16*)w;    w += szXPf;
        u16*   GFb   = (u16*)w;    w += szGF;
        u16*   PIUa  = (u16*)w;    w += szPIU;
        u16*   PIUc  = (u16*)w;    w += szPIU2;
        u16*   HSB   = (u16*)w;    w += szHSB;
        u16*   xb    = (u16*)w;    w += szXB;
        u16*   WXb   = (u16*)w;    w += szWX;
        u16*   WHb   = (u16*)w;    w += szWH;
        float* iemb  = (float*)w;  w += szIE;
        float* femb  = (float*)w;  w += szFE;
        float* ibc   = (float*)w;  w += szIB;
        float* fbc   = (float*)w;  w += szFB;

        // 1) vectorized bf16 conversion
        hipLaunchKernelGGL(convert_vec_kernel, dim3(CV_TOT / 256), dim3(256), 0, stream,
                           x, iux_w, fx_w, iuh_w, fh_w, xb, WXb, WHb);

        // 2) XP dual GEMM + emb projection + biases
        {
            const int gx1 = N_NODES / 128, n1 = gx1 * (1024 / 128);
            const int gx2 = (NINT + 127) / 128;
            const int nG  = n1 + gx2 * (512 / 128);
            hipLaunchKernelGGL(xp_gemm_emb_kernel, dim3(nG + 385), dim3(256), 0, stream,
                               xb, WXb, XPiub, XPfb, gx1, n1, gx2, nG,
                               demb, iue_w, fe_w, iux_b, iuh_b, iue_b,
                               fx_b, fh_b, fe_b, iemb, femb, ibc, fbc);
        }

        // 3) leaves + hsum for level 1
        hipLaunchKernelGGL(fused_leaf_kernel, dim3(lvlN[1]), dim3(256), 0, stream,
                           XPiub, iemb, ibc, cidx, mh, Hb, HSB, lvlLo[1]);

        // 4) GEMM(1): GF[leaves] + PIU[level1]
        {
            const int gx1 = (lvlN[0] + 127) / 128, n1 = gx1 * (512 / 128);
            const int gx2 = (lvlN[1] + 127) / 128, n2 = gx2 * (1024 / 128);
            hipLaunchKernelGGL(gemm_bf16_dual_kernel, dim3(n1 + n2), dim3(256), 0, stream,
                               Hb, HD, WHb + (size_t)1024 * HD, HD,
                               GFb, HD, lvlN[0], HD, gx1, n1,
                               HSB, HD, WHb, HD, PIUa, 1024, lvlN[1], HD, gx2);
        }
        // 5) combine(1): writes Hb[level1] + HSB for level-2 parents
        hipLaunchKernelGGL(fused_combine_kernel, dim3(lvlN[2]), dim3(256), 0, stream,
                           XPiub, XPfb, PIUa, GFb, cidx, cdep, mh, me,
                           iemb, femb, ibc, fbc, Hb, HSB,
                           lvlLo[1], lvlLo[2], 0, (float*)d_out);

        // 6) GEMM(2): GF[level1] + PIU[level2]
        {
            const int gx1 = (lvlN[1] + 127) / 128, n1 = gx1 * (512 / 128);
            const int gx2 = (lvlN[2] + 127) / 128, n2 = gx2 * (1024 / 128);
            hipLaunchKernelGGL(gemm_bf16_dual_kernel, dim3(n1 + n2), dim3(256), 0, stream,
                               Hb + (size_t)lvlLo[1] * HD, HD, WHb + (size_t)1024 * HD, HD,
                               GFb + (size_t)lvlLo[1] * HD, HD, lvlN[1], HD, gx1, n1,
                               HSB, HD, WHb, HD, PIUa, 1024, lvlN[2], HD, gx2);
        }

        // 7..11) FCP chain: levels 2..6 (combine + inline GF/PIU projections)
        u16* piuIn  = PIUa;
        u16* piuOut = PIUc;
        for (int l = 2; l <= 6; ++l) {
            hipLaunchKernelGGL(fcp_kernel, dim3(lvlN[l + 1]), dim3(256), 0, stream,
                               XPiub, XPfb, piuIn, GFb, cidx, cdep, mh, me,
                               iemb, femb, ibc, fbc, Hb, iuh_w, fh_w,
                               piuOut, lvlLo[l], lvlLo[l + 1]);
            u16* tmp = piuIn; piuIn = piuOut; piuOut = tmp;
        }

        // 12) root combine -> d_out
        hipLaunchKernelGGL(fused_combine_kernel, dim3(1), dim3(256), 0, stream,
                           XPiub, XPfb, piuIn, GFb, cidx, cdep, mh, me,
                           iemb, femb, ibc, fbc, Hb, HSB,
                           lvlLo[7], 0, 1, (float*)d_out);
        return;
    }

    // ---- fallback: fused fp32 path (~34 MB ws) ----
    float* ws   = (float*)d_ws;
    float* H    = ws;
    float* iembF = H + (size_t)N_NODES * HD;
    float* fembF = iembF + (size_t)NDEP * 1024;
    float* ibcF  = fembF + (size_t)NDEP * HD;
    float* fbcF  = ibcF + 1024;

    hipLaunchKernelGGL(emb_setup_kernel, dim3(NDEP), dim3(256), 0, stream,
                       demb, iue_w, fe_w, iux_b, iuh_b, iue_b, fx_b, fh_b, fe_b,
                       iembF, fembF, ibcF, fbcF);
    for (int l = 0; l < 8; ++l) {
        dim3 grid((lvlN[l] + LM - 1) / LM, HD / LCOL);
        hipLaunchKernelGGL(level_kernel, grid, dim3(256), 0, stream,
                           x, cidx, cdep, mh, me, iux_w, iuh_w, fx_w, fh_w,
                           iembF, fembF, ibcF, fbcF, H, lvlLo[l], lvlLo[l] + lvlN[l]);
    }
    hipLaunchKernelGGL(copy_out_kernel, dim3(2), dim3(256), 0, stream, H, (float*)d_out);
}

// Round 10
// 245.951 us; speedup vs baseline: 4.1673x; 4.1673x over previous
//
#include <hip/hip_runtime.h>
#include <cstddef>

#define N_NODES 16384
#define HD      512
#define INDIM   300
#define INP     320
#define NDEP    48
#define NLEAF   10923
#define NINT    5461
#define KT      32
#define LM      16
#define LCOL    128

typedef unsigned int u32;
typedef unsigned short u16;
typedef __attribute__((ext_vector_type(8))) short short8;
typedef __attribute__((ext_vector_type(4))) float f32x4;

typedef __attribute__((address_space(1))) const u32 as1_u32;
typedef __attribute__((address_space(3))) u32 as3_u32;

__device__ __forceinline__ float sigmoidf_(float v) {
    return 1.f / (1.f + __expf(-v));
}
__device__ __forceinline__ float tanhf_(float v) {
    v = fminf(15.f, fmaxf(-15.f, v));
    const float e = __expf(2.f * v);
    return (e - 1.f) / (e + 1.f);
}
__device__ __forceinline__ u16 f2bf(float f) {
    u32 u = __float_as_uint(f);
    u32 r = (u + 0x7fffu + ((u >> 16) & 1u)) >> 16;
    return (u16)r;
}
__device__ __forceinline__ float b2f(u16 v) {
    return __uint_as_float((u32)v << 16);
}
__device__ __forceinline__ u32 pack2(float a, float b) {
    return (u32)f2bf(a) | ((u32)f2bf(b) << 16);
}

// ---------------------------------------------------------------------------
// vectorized fp32->bf16 convert (rows 1200B = 75x16B => float4 clean)
// ---------------------------------------------------------------------------
#define RA  (N_NODES * 75)
#define RB  (N_NODES * 10)
#define RC1 (1536 * 75)
#define RC2 (1536 * 10)
#define RD  (1536 * 128)
#define CV_TOT (RA + RB + RC1 + RC2 + RD)

__global__ __launch_bounds__(256)
void convert_vec_kernel(const float* __restrict__ x,
                        const float* __restrict__ iux_w, const float* __restrict__ fx_w,
                        const float* __restrict__ iuh_w, const float* __restrict__ fh_w,
                        u16* __restrict__ xb, u16* __restrict__ WXb, u16* __restrict__ WHb)
{
    int idx = blockIdx.x * 256 + threadIdx.x;
    if (idx < RA) {
        const int r = idx / 75, k4 = idx - r * 75;
        const float4 v = *reinterpret_cast<const float4*>(x + (size_t)r * INDIM + k4 * 4);
        *reinterpret_cast<uint2*>(&xb[(size_t)r * INP + k4 * 4]) =
            make_uint2(pack2(v.x, v.y), pack2(v.z, v.w));
        return;
    }
    idx -= RA;
    if (idx < RB) {
        const int r = idx / 10, j = idx - r * 10;
        reinterpret_cast<u32*>(xb)[(size_t)r * 160 + 150 + j] = 0u;
        return;
    }
    idx -= RB;
    if (idx < RC1) {
        const int r = idx / 75, k4 = idx - r * 75;
        const float* src = (r < 1024) ? (iux_w + (size_t)r * INDIM)
                                      : (fx_w + (size_t)(r - 1024) * INDIM);
        const float4 v = *reinterpret_cast<const float4*>(src + k4 * 4);
        *reinterpret_cast<uint2*>(&WXb[(size_t)r * INP + k4 * 4]) =
            make_uint2(pack2(v.x, v.y), pack2(v.z, v.w));
        return;
    }
    idx -= RC1;
    if (idx < RC2) {
        const int r = idx / 10, j = idx - r * 10;
        reinterpret_cast<u32*>(WXb)[(size_t)r * 160 + 150 + j] = 0u;
        return;
    }
    idx -= RC2;
    {
        const int r = idx >> 7, k4 = idx & 127;
        const float* src = (r < 1024) ? (iuh_w + (size_t)r * HD)
                                      : (fh_w + (size_t)(r - 1024) * HD);
        const float4 v = *reinterpret_cast<const float4*>(src + k4 * 4);
        *reinterpret_cast<uint2*>(&WHb[(size_t)r * HD + k4 * 4]) =
            make_uint2(pack2(v.x, v.y), pack2(v.z, v.w));
    }
}

// ---------------------------------------------------------------------------
// bf16 MFMA GEMM body: C[M][N] (bf16) = A[M][K] @ B[N][K]^T
// 128x128 tile, BK=64, 4 waves (2x2), 16x16x32 MFMA, global_load_lds(16B),
// XOR chunk-swizzle. Requires K%64==0, N%128==0.
// ---------------------------------------------------------------------------
__device__ __forceinline__
void gemm_body(u16* As, u16* Bs,
               const u16* __restrict__ A, int lda,
               const u16* __restrict__ B, int ldb,
               u16* __restrict__ C, int ldc,
               int M, int K, int bx, int by)
{
    const int tid  = threadIdx.x;
    const int lane = tid & 63;
    const int wave = tid >> 6;
    const int mBlk = bx * 128;
    const int nBlk = by * 128;

    const int wr = (wave >> 1) * 64;
    const int wc = (wave & 1) * 64;
    const int fr = lane & 15;
    const int kg = lane >> 4;

    f32x4 acc[4][4];
    #pragma unroll
    for (int i = 0; i < 4; ++i)
        #pragma unroll
        for (int j = 0; j < 4; ++j) acc[i][j] = (f32x4){0.f, 0.f, 0.f, 0.f};

    int offA[4], offB[4];
    #pragma unroll
    for (int it = 0; it < 4; ++it) {
        const int s   = it * 256 + tid;
        const int row = s >> 3, c = s & 7;
        const int cs  = c ^ (row & 7);
        int ga = mBlk + row; if (ga > M - 1) ga = M - 1;
        offA[it] = ga * lda + cs * 8;
        offB[it] = (nBlk + row) * ldb + cs * 8;
    }

    for (int k0 = 0; k0 < K; k0 += 64) {
        #pragma unroll
        for (int it = 0; it < 4; ++it) {
            const int ldsOff = (it * 256 + wave * 64) * 8;
            __builtin_amdgcn_global_load_lds((as1_u32*)(A + offA[it] + k0),
                                             (as3_u32*)(&As[ldsOff]), 16, 0, 0);
            __builtin_amdgcn_global_load_lds((as1_u32*)(B + offB[it] + k0),
                                             (as3_u32*)(&Bs[ldsOff]), 16, 0, 0);
        }
        __syncthreads();
        #pragma unroll
        for (int half = 0; half < 2; ++half) {
            const int ckb = half * 4 + kg;
            short8 af[4], bf[4];
            #pragma unroll
            for (int f = 0; f < 4; ++f) {
                const int ar = wr + f * 16 + fr;
                af[f] = *(const short8*)&As[ar * 64 + ((ckb ^ (ar & 7)) * 8)];
                const int br = wc + f * 16 + fr;
                bf[f] = *(const short8*)&Bs[br * 64 + ((ckb ^ (br & 7)) * 8)];
            }
            #pragma unroll
            for (int mi = 0; mi < 4; ++mi)
                #pragma unroll
                for (int ni = 0; ni < 4; ++ni)
                    acc[mi][ni] = __builtin_amdgcn_mfma_f32_16x16x32_bf16(
                                      af[mi], bf[ni], acc[mi][ni], 0, 0, 0);
        }
        __syncthreads();
    }

    #pragma unroll
    for (int mi = 0; mi < 4; ++mi) {
        const int r0 = mBlk + wr + mi * 16 + kg * 4;
        #pragma unroll
        for (int v = 0; v < 4; ++v) {
            const int r = r0 + v;
            if (r >= M) continue;
            u16* crow = C + (size_t)r * ldc + nBlk + wc + fr;
            #pragma unroll
            for (int ni = 0; ni < 4; ++ni)
                crow[ni * 16] = f2bf(acc[mi][ni][v]);
        }
    }
}

// ---------------------------------------------------------------------------
// XP dual GEMM + emb projection + biases in ONE dispatch. 4 blocks/CU.
// ---------------------------------------------------------------------------
__global__ __launch_bounds__(256, 4)
void xp_gemm_emb_kernel(const u16* __restrict__ xb, const u16* __restrict__ WXb,
                        u16* __restrict__ XPiub, u16* __restrict__ XPfb,
                        int gx1, int n1, int gx2, int nG,
                        const float* __restrict__ demb,
                        const float* __restrict__ iue_w, const float* __restrict__ fe_w,
                        const float* __restrict__ iux_b, const float* __restrict__ iuh_b,
                        const float* __restrict__ iue_b, const float* __restrict__ fx_b,
                        const float* __restrict__ fh_b, const float* __restrict__ fe_b,
                        float* __restrict__ iemb, float* __restrict__ femb,
                        float* __restrict__ ibc, float* __restrict__ fbc)
{
    __shared__ u16 As[128 * 64];
    __shared__ u16 Bs[128 * 64];
    const int flat = blockIdx.x;
    if (flat < nG) {
        if (flat < n1) {
            gemm_body(As, Bs, xb, INP, WXb, INP, XPiub, 1024, N_NODES, INP,
                      flat % gx1, flat / gx1);
        } else {
            const int f2 = flat - n1;
            gemm_body(As, Bs, xb + (size_t)NLEAF * INP, INP,
                      WXb + (size_t)1024 * INP, INP, XPfb, 512, NINT, INP,
                      f2 % gx2, f2 / gx2);
        }
        return;
    }
    const int bo  = flat - nG;            // [0, 385)
    const int tid = threadIdx.x;
    if (bo == 384) {
        for (int o = tid; o < 1024; o += 256) ibc[o] = iux_b[o] + iuh_b[o] + iue_b[o];
        for (int o = tid; o < 512;  o += 256) fbc[o] = fx_b[o] + fh_b[o] + fe_b[o];
        return;
    }
    const int wave = tid >> 6;
    const int d    = tid & 63;
    const bool isI = (bo < 256);
    const int o    = (isI ? bo : bo - 256) * 4 + wave;
    if (d >= NDEP) return;
    const float* wrow = isI ? (iue_w + (size_t)o * HD) : (fe_w + (size_t)o * HD);
    const float* drow = demb + (size_t)d * HD;

    float4 a0 = make_float4(0.f, 0.f, 0.f, 0.f);
    float4 a1 = make_float4(0.f, 0.f, 0.f, 0.f);
    for (int k = 0; k < HD; k += 8) {
        const float4 wv0 = *reinterpret_cast<const float4*>(wrow + k);
        const float4 wv1 = *reinterpret_cast<const float4*>(wrow + k + 4);
        const float4 dv0 = *reinterpret_cast<const float4*>(drow + k);
        const float4 dv1 = *reinterpret_cast<const float4*>(drow + k + 4);
        a0.x = fmaf(dv0.x, wv0.x, a0.x); a0.y = fmaf(dv0.y, wv0.y, a0.y);
        a0.z = fmaf(dv0.z, wv0.z, a0.z); a0.w = fmaf(dv0.w, wv0.w, a0.w);
        a1.x = fmaf(dv1.x, wv1.x, a1.x); a1.y = fmaf(dv1.y, wv1.y, a1.y);
        a1.z = fmaf(dv1.z, wv1.z, a1.z); a1.w = fmaf(dv1.w, wv1.w, a1.w);
    }
    const float s = ((a0.x + a0.y) + (a0.z + a0.w)) + ((a1.x + a1.y) + (a1.z + a1.w));
    if (isI) iemb[(size_t)d * 1024 + o] = s;
    else     femb[(size_t)d * 512  + o] = s;
}

// Two GEMM jobs in one dispatch (flat 1-D grid split) — level loop. 4 blk/CU.
__global__ __launch_bounds__(256, 4)
void gemm_bf16_dual_kernel(const u16* __restrict__ A1, int lda1,
                           const u16* __restrict__ B1, int ldb1,
                           u16* __restrict__ C1, int ldc1, int M1, int K1,
                           int gx1, int n1,
                           const u16* __restrict__ A2, int lda2,
                           const u16* __restrict__ B2, int ldb2,
                           u16* __restrict__ C2, int ldc2, int M2, int K2,
                           int gx2)
{
    __shared__ u16 As[128 * 64];
    __shared__ u16 Bs[128 * 64];
    const int flat = blockIdx.x;
    if (flat < n1) {
        gemm_body(As, Bs, A1, lda1, B1, ldb1, C1, ldc1, M1, K1,
                  flat % gx1, flat / gx1);
    } else {
        const int f2 = flat - n1;
        gemm_body(As, Bs, A2, lda2, B2, ldb2, C2, ldc2, M2, K2,
                  f2 % gx2, f2 / gx2);
    }
}

// ---------------------------------------------------------------------------
// fused leaf + hsum: block g owns parent p = loNext+g (level-1 node), computes
// h for its <=4 leaf children, writes Hb, and HSB[g] = sum(h).
// ---------------------------------------------------------------------------
__global__ __launch_bounds__(256)
void fused_leaf_kernel(const u16* __restrict__ XPiub,
                       const float* __restrict__ iemb, const float* __restrict__ ibc,
                       const int* __restrict__ cidx, const float* __restrict__ mh,
                       u16* __restrict__ Hb, u16* __restrict__ HSB, int loNext)
{
    const int g   = blockIdx.x;
    const int p   = loNext + g;
    const int j2  = threadIdx.x * 2;

    int ct[4]; float cm[4];
    #pragma unroll
    for (int c = 0; c < 4; ++c) { ct[c] = cidx[p * 4 + c]; cm[c] = mh[p * 4 + c]; }

    const float2 ibci = *reinterpret_cast<const float2*>(&ibc[j2]);
    const float2 ibcu = *reinterpret_cast<const float2*>(&ibc[512 + j2]);
    const float2 iei  = *reinterpret_cast<const float2*>(&iemb[j2]);
    const float2 ieu  = *reinterpret_cast<const float2*>(&iemb[512 + j2]);

    float hs0 = 0.f, hs1 = 0.f;
    #pragma unroll
    for (int c = 0; c < 4; ++c) {
        if (cm[c] == 0.f) continue;
        const int t = ct[c];
        const u32 xi = *reinterpret_cast<const u32*>(&XPiub[(size_t)t * 1024 + j2]);
        const u32 xu = *reinterpret_cast<const u32*>(&XPiub[(size_t)t * 1024 + 512 + j2]);
        const float h0 = tanhf_(sigmoidf_(b2f((u16)xi) + iei.x + ibci.x)
                                * tanhf_(b2f((u16)xu) + ieu.x + ibcu.x));
        const float h1 = tanhf_(sigmoidf_(b2f((u16)(xi >> 16)) + iei.y + ibci.y)
                                * tanhf_(b2f((u16)(xu >> 16)) + ieu.y + ibcu.y));
        *reinterpret_cast<u32*>(&Hb[(size_t)t * 512 + j2]) = pack2(h0, h1);
        hs0 += h0; hs1 += h1;
    }
    *reinterpret_cast<u32*>(&HSB[(size_t)g * 512 + j2]) = pack2(hs0, hs1);
}

// ---------------------------------------------------------------------------
// fused combine + hsum for level l: block g owns parent p = loNext+g (level
// l+1); full gate math for its <=4 level-l children; writes Hb + HSB[g].
// Child hidden states for the f-path are read from Hb (bf16).
// isRoot: grid=1, node 16383, writes d_out (f32).
// ---------------------------------------------------------------------------
__global__ __launch_bounds__(256)
void fused_combine_kernel(const u16* __restrict__ XPiub, const u16* __restrict__ XPfb,
                          const u16* __restrict__ PIUb, const u16* __restrict__ GFb,
                          const int* __restrict__ cidx, const int* __restrict__ cdep,
                          const float* __restrict__ mh, const float* __restrict__ me,
                          const float* __restrict__ iemb, const float* __restrict__ femb,
                          const float* __restrict__ ibc, const float* __restrict__ fbc,
                          u16* __restrict__ Hb, u16* __restrict__ HSB,
                          int lo, int loNext, int isRoot, float* __restrict__ outp)
{
    const int j2 = threadIdx.x * 2;

    int ct[4]; float cm[4];
    if (isRoot) {
        ct[0] = N_NODES - 1; cm[0] = 1.f;
        ct[1] = ct[2] = ct[3] = 0; cm[1] = cm[2] = cm[3] = 0.f;
    } else {
        const int p = loNext + blockIdx.x;
        #pragma unroll
        for (int c = 0; c < 4; ++c) { ct[c] = cidx[p * 4 + c]; cm[c] = mh[p * 4 + c]; }
    }

    const float2 ibci = *reinterpret_cast<const float2*>(&ibc[j2]);
    const float2 ibcu = *reinterpret_cast<const float2*>(&ibc[512 + j2]);
    const float2 fbc2 = *reinterpret_cast<const float2*>(&fbc[j2]);

    float hs0 = 0.f, hs1 = 0.f;
    #pragma unroll
    for (int c = 0; c < 4; ++c) {
        if (cm[c] == 0.f) continue;
        const int t = ct[c];

        int ci2[4], dp2[4]; float m2[4], e2[4];
        #pragma unroll
        for (int k = 0; k < 4; ++k) {
            ci2[k] = cidx[t * 4 + k]; dp2[k] = cdep[t * 4 + k];
            m2[k]  = mh[t * 4 + k];   e2[k]  = me[t * 4 + k];
        }

        float ei0 = 0.f, ei1 = 0.f, eu0 = 0.f, eu1 = 0.f;
        #pragma unroll
        for (int k = 0; k < 4; ++k) {
            if (e2[k] != 0.f) {
                const float* ie = iemb + (size_t)dp2[k] * 1024;
                const float2 a = *reinterpret_cast<const float2*>(&ie[j2]);
                const float2 b = *reinterpret_cast<const float2*>(&ie[512 + j2]);
                ei0 = fmaf(e2[k], a.x, ei0); ei1 = fmaf(e2[k], a.y, ei1);
                eu0 = fmaf(e2[k], b.x, eu0); eu1 = fmaf(e2[k], b.y, eu1);
            }
        }

        const u32 xi = *reinterpret_cast<const u32*>(&XPiub[(size_t)t * 1024 + j2]);
        const u32 xu = *reinterpret_cast<const u32*>(&XPiub[(size_t)t * 1024 + 512 + j2]);
        const u32 pi = *reinterpret_cast<const u32*>(&PIUb[(size_t)(t - lo) * 1024 + j2]);
        const u32 pu = *reinterpret_cast<const u32*>(&PIUb[(size_t)(t - lo) * 1024 + 512 + j2]);
        const u32 xf = *reinterpret_cast<const u32*>(&XPfb[(size_t)(t - NLEAF) * 512 + j2]);

        const float iu_i0 = b2f((u16)xi) + b2f((u16)pi) + ibci.x + ei0;
        const float iu_i1 = b2f((u16)(xi >> 16)) + b2f((u16)(pi >> 16)) + ibci.y + ei1;
        const float iu_u0 = b2f((u16)xu) + b2f((u16)pu) + ibcu.x + eu0;
        const float iu_u1 = b2f((u16)(xu >> 16)) + b2f((u16)(pu >> 16)) + ibcu.y + eu1;
        const float xf0 = b2f((u16)xf) + fbc2.x;
        const float xf1 = b2f((u16)(xf >> 16)) + fbc2.y;

        float fcs0 = 0.f, fcs1 = 0.f;
        #pragma unroll
        for (int k = 0; k < 4; ++k) {
            if (m2[k] != 0.f) {
                const u32 gf = *reinterpret_cast<const u32*>(&GFb[(size_t)ci2[k] * 512 + j2]);
                const u32 hb = *reinterpret_cast<const u32*>(&Hb[(size_t)ci2[k] * 512 + j2]);
                const float2 fe = *reinterpret_cast<const float2*>(&femb[(size_t)dp2[k] * 512 + j2]);
                const float fv0 = b2f((u16)gf) + xf0 + fe.x;
                const float fv1 = b2f((u16)(gf >> 16)) + xf1 + fe.y;
                fcs0 = fmaf(sigmoidf_(fv0), m2[k] * b2f((u16)hb), fcs0);
                fcs1 = fmaf(sigmoidf_(fv1), m2[k] * b2f((u16)(hb >> 16)), fcs1);
            }
        }

        const float h0 = tanhf_(fmaf(sigmoidf_(iu_i0), tanhf_(iu_u0), fcs0));
        const float h1 = tanhf_(fmaf(sigmoidf_(iu_i1), tanhf_(iu_u1), fcs1));
        *reinterpret_cast<u32*>(&Hb[(size_t)t * 512 + j2]) = pack2(h0, h1);
        hs0 += h0; hs1 += h1;
        if (isRoot) *reinterpret_cast<float2*>(&outp[j2]) = make_float2(h0, h1);
    }
    if (!isRoot)
        *reinterpret_cast<u32*>(&HSB[(size_t)blockIdx.x * 512 + j2]) = pack2(hs0, hs1);
}

// ===========================================================================
// FALLBACK (round-1 fused fp32 path, needs only ~34 MB ws)
// ===========================================================================
__global__ __launch_bounds__(256)
void emb_setup_kernel(const float* __restrict__ demb,
                      const float* __restrict__ iue_w,
                      const float* __restrict__ fe_w,
                      const float* __restrict__ iux_b,
                      const float* __restrict__ iuh_b,
                      const float* __restrict__ iue_b,
                      const float* __restrict__ fx_b,
                      const float* __restrict__ fh_b,
                      const float* __restrict__ fe_b,
                      float* __restrict__ iemb,
                      float* __restrict__ femb,
                      float* __restrict__ ibc,
                      float* __restrict__ fbc)
{
    const int d   = blockIdx.x;
    const int tid = threadIdx.x;
    __shared__ float sd[HD];
    sd[tid]       = demb[d * HD + tid];
    sd[tid + 256] = demb[d * HD + 256 + tid];
    __syncthreads();

    #pragma unroll
    for (int r = 0; r < 4; ++r) {
        const int o = r * 256 + tid;
        const float* w = iue_w + (size_t)o * HD;
        float acc = 0.f;
        for (int k = 0; k < HD; k += 4) {
            const float4 wv = *reinterpret_cast<const float4*>(w + k);
            acc += sd[k] * wv.x + sd[k + 1] * wv.y + sd[k + 2] * wv.z + sd[k + 3] * wv.w;
        }
        iemb[(size_t)d * 1024 + o] = acc;
    }
    #pragma unroll
    for (int r = 0; r < 2; ++r) {
        const int o = r * 256 + tid;
        const float* w = fe_w + (size_t)o * HD;
        float acc = 0.f;
        for (int k = 0; k < HD; k += 4) {
            const float4 wv = *reinterpret_cast<const float4*>(w + k);
            acc += sd[k] * wv.x + sd[k + 1] * wv.y + sd[k + 2] * wv.z + sd[k + 3] * wv.w;
        }
        femb[(size_t)d * HD + o] = acc;
    }
    if (d == 0) {
        #pragma unroll
        for (int r = 0; r < 4; ++r) { const int o = r * 256 + tid; ibc[o] = iux_b[o] + iuh_b[o] + iue_b[o]; }
        #pragma unroll
        for (int r = 0; r < 2; ++r) { const int o = r * 256 + tid; fbc[o] = fx_b[o] + fh_b[o] + fe_b[o]; }
    }
}

__global__ __launch_bounds__(256, 2)
void level_kernel(const float* __restrict__ x,
                  const int*   __restrict__ child_idx,
                  const int*   __restrict__ child_dep,
                  const float* __restrict__ mask_h,
                  const float* __restrict__ mask_e,
                  const float* __restrict__ iux_w,
                  const float* __restrict__ iuh_w,
                  const float* __restrict__ fx_w,
                  const float* __restrict__ fh_w,
                  const float* __restrict__ iemb,
                  const float* __restrict__ femb,
                  const float* __restrict__ ibc,
                  const float* __restrict__ fbc,
                  float* __restrict__ H,
                  int tLo, int tEnd)
{
    __shared__ __align__(16) float sA[KT][68];
    __shared__ float sWI[KT][LCOL + 1];
    __shared__ float sWU[KT][LCOL + 1];
    __shared__ float sWF[KT][LCOL + 1];
    __shared__ int   sCidx[LM][4];
    __shared__ float sMh[LM][4];
    __shared__ int   sDep[LM][4];
    __shared__ float sMe[LM][4];

    const int tid  = threadIdx.x;
    const int base = tLo + blockIdx.x * LM;
    const int j0   = blockIdx.y * LCOL;

    if (tid < LM * 4) {
        const int m = tid >> 2, c = tid & 3;
        const int t = base + m;
        const bool v = (t < tEnd);
        sCidx[m][c] = v ? child_idx[t * 4 + c] : 0;
        sMh[m][c]   = v ? mask_h[t * 4 + c]    : 0.f;
        sDep[m][c]  = v ? child_dep[t * 4 + c] : 0;
        sMe[m][c]   = v ? mask_e[t * 4 + c]    : 0.f;
    }

    const int jj = tid & 63;
    const int mg = tid >> 6;

    float acc_i[4][2], acc_u[4][2], acc_fx[4][2], acc_f[4][2][4];
    #pragma unroll
    for (int mm = 0; mm < 4; ++mm)
        #pragma unroll
        for (int c2 = 0; c2 < 2; ++c2) {
            acc_i[mm][c2] = 0.f; acc_u[mm][c2] = 0.f; acc_fx[mm][c2] = 0.f;
            #pragma unroll
            for (int c = 0; c < 4; ++c) acc_f[mm][c2][c] = 0.f;
        }

    __syncthreads();

    for (int k0 = 0; k0 < HD; k0 += KT) {
        #pragma unroll
        for (int it = 0; it < 2; ++it) {
            const int chunk = tid + it * 256;
            const int mc = chunk >> 3;
            const int kk = (chunk & 7) * 4;
            const int m = mc >> 2, c = mc & 3;
            const float mhv = sMh[m][c];
            float4 v = make_float4(0.f, 0.f, 0.f, 0.f);
            if (mhv != 0.f)
                v = *reinterpret_cast<const float4*>(H + (size_t)sCidx[m][c] * HD + k0 + kk);
            sA[kk + 0][mc] = v.x; sA[kk + 1][mc] = v.y; sA[kk + 2][mc] = v.z; sA[kk + 3][mc] = v.w;
        }
        #pragma unroll
        for (int it = 0; it < 4; ++it) {
            const int chunk = tid + it * 256;
            const int row = chunk >> 3;
            const int kk = (chunk & 7) * 4;
            const float4 vI = *reinterpret_cast<const float4*>(iuh_w + (size_t)(j0 + row) * HD + k0 + kk);
            const float4 vU = *reinterpret_cast<const float4*>(iuh_w + (size_t)(j0 + row + 512) * HD + k0 + kk);
            const float4 vF = *reinterpret_cast<const float4*>(fh_w  + (size_t)(j0 + row) * HD + k0 + kk);
            sWI[kk + 0][row] = vI.x; sWI[kk + 1][row] = vI.y; sWI[kk + 2][row] = vI.z; sWI[kk + 3][row] = vI.w;
            sWU[kk + 0][row] = vU.x; sWU[kk + 1][row] = vU.y; sWU[kk + 2][row] = vU.z; sWU[kk + 3][row] = vU.w;
            sWF[kk + 0][row] = vF.x; sWF[kk + 1][row] = vF.y; sWF[kk + 2][row] = vF.z; sWF[kk + 3][row] = vF.w;
        }
        __syncthreads();
        #pragma unroll 4
        for (int k = 0; k < KT; ++k) {
            const float wi0 = sWI[k][jj], wi1 = sWI[k][jj + 64];
            const float wu0 = sWU[k][jj], wu1 = sWU[k][jj + 64];
            const float wf0 = sWF[k][jj], wf1 = sWF[k][jj + 64];
            #pragma unroll
            for (int mm = 0; mm < 4; ++mm) {
                const int m = mg + mm * 4;
                const float4 cv = *reinterpret_cast<const float4*>(&sA[k][m * 4]);
                const float hs = (cv.x + cv.y) + (cv.z + cv.w);
                acc_i[mm][0] = fmaf(hs, wi0, acc_i[mm][0]);
                acc_i[mm][1] = fmaf(hs, wi1, acc_i[mm][1]);
                acc_u[mm][0] = fmaf(hs, wu0, acc_u[mm][0]);
                acc_u[mm][1] = fmaf(hs, wu1, acc_u[mm][1]);
                acc_f[mm][0][0] = fmaf(cv.x, wf0, acc_f[mm][0][0]);
                acc_f[mm][1][0] = fmaf(cv.x, wf1, acc_f[mm][1][0]);
                acc_f[mm][0][1] = fmaf(cv.y, wf0, acc_f[mm][0][1]);
                acc_f[mm][1][1] = fmaf(cv.y, wf1, acc_f[mm][1][1]);
                acc_f[mm][0][2] = fmaf(cv.z, wf0, acc_f[mm][0][2]);
                acc_f[mm][1][2] = fmaf(cv.z, wf1, acc_f[mm][1][2]);
                acc_f[mm][0][3] = fmaf(cv.w, wf0, acc_f[mm][0][3]);
                acc_f[mm][1][3] = fmaf(cv.w, wf1, acc_f[mm][1][3]);
            }
        }
        __syncthreads();
    }

    for (int k0 = 0; k0 < INDIM; k0 += KT) {
        if (tid < 128) {
            const int m = tid >> 3;
            const int kk = (tid & 7) * 4;
            const int t = base + m;
            float4 v = make_float4(0.f, 0.f, 0.f, 0.f);
            if (t < tEnd && (k0 + kk + 3) < INDIM)
                v = *reinterpret_cast<const float4*>(x + (size_t)t * INDIM + k0 + kk);
            sA[kk + 0][m] = v.x; sA[kk + 1][m] = v.y; sA[kk + 2][m] = v.z; sA[kk + 3][m] = v.w;
        }
        #pragma unroll
        for (int it = 0; it < 4; ++it) {
            const int chunk = tid + it * 256;
            const int row = chunk >> 3;
            const int kk = (chunk & 7) * 4;
            float4 vI = make_float4(0.f, 0.f, 0.f, 0.f), vU = vI, vF = vI;
            if ((k0 + kk + 3) < INDIM) {
                vI = *reinterpret_cast<const float4*>(iux_w + (size_t)(j0 + row) * INDIM + k0 + kk);
                vU = *reinterpret_cast<const float4*>(iux_w + (size_t)(j0 + row + 512) * INDIM + k0 + kk);
                vF = *reinterpret_cast<const float4*>(fx_w  + (size_t)(j0 + row) * INDIM + k0 + kk);
            }
            sWI[kk + 0][row] = vI.x; sWI[kk + 1][row] = vI.y; sWI[kk + 2][row] = vI.z; sWI[kk + 3][row] = vI.w;
            sWU[kk + 0][row] = vU.x; sWU[kk + 1][row] = vU.y; sWU[kk + 2][row] = vU.z; sWU[kk + 3][row] = vU.w;
            sWF[kk + 0][row] = vF.x; sWF[kk + 1][row] = vF.y; sWF[kk + 2][row] = vF.z; sWF[kk + 3][row] = vF.w;
        }
        __syncthreads();
        #pragma unroll 4
        for (int k = 0; k < KT; ++k) {
            const float wi0 = sWI[k][jj], wi1 = sWI[k][jj + 64];
            const float wu0 = sWU[k][jj], wu1 = sWU[k][jj + 64];
            const float wf0 = sWF[k][jj], wf1 = sWF[k][jj + 64];
            #pragma unroll
            for (int mm = 0; mm < 4; ++mm) {
                const float xv = sA[k][mg + mm * 4];
                acc_i[mm][0]  = fmaf(xv, wi0, acc_i[mm][0]);
                acc_i[mm][1]  = fmaf(xv, wi1, acc_i[mm][1]);
                acc_u[mm][0]  = fmaf(xv, wu0, acc_u[mm][0]);
                acc_u[mm][1]  = fmaf(xv, wu1, acc_u[mm][1]);
                acc_fx[mm][0] = fmaf(xv, wf0, acc_fx[mm][0]);
                acc_fx[mm][1] = fmaf(xv, wf1, acc_fx[mm][1]);
            }
        }
        __syncthreads();
    }

    #pragma unroll
    for (int mm = 0; mm < 4; ++mm) {
        const int m = mg + mm * 4;
        const int t = base + m;
        if (t >= tEnd) continue;
        #pragma unroll
        for (int c2 = 0; c2 < 2; ++c2) {
            const int j = j0 + c2 * 64 + jj;
            float emb_i = 0.f, emb_u = 0.f;
            #pragma unroll
            for (int c = 0; c < 4; ++c) {
                const float mev = sMe[m][c];
                if (mev != 0.f) {
                    const float* ie = iemb + (size_t)sDep[m][c] * 1024;
                    emb_i = fmaf(mev, ie[j], emb_i);
                    emb_u = fmaf(mev, ie[j + 512], emb_u);
                }
            }
            const float iu_i = acc_i[mm][c2] + ibc[j] + emb_i;
            const float iu_u = acc_u[mm][c2] + ibc[j + 512] + emb_u;
            const float ig = sigmoidf_(iu_i);
            const float uu = tanhf_(iu_u);
            float fcs = 0.f;
            #pragma unroll
            for (int c = 0; c < 4; ++c) {
                const float mhv = sMh[m][c];
                if (mhv != 0.f) {
                    const float fv = acc_f[mm][c2][c] + acc_fx[mm][c2] + fbc[j]
                                   + femb[(size_t)sDep[m][c] * HD + j];
                    const float fg = sigmoidf_(fv);
                    const float chj = H[(size_t)sCidx[m][c] * HD + j] * mhv;
                    fcs = fmaf(fg, chj, fcs);
                }
            }
            H[(size_t)t * HD + j] = tanhf_(fmaf(ig, uu, fcs));
        }
    }
}

__global__ void copy_out_kernel(const float* __restrict__ H, float* __restrict__ out) {
    const int j = blockIdx.x * 256 + threadIdx.x;
    if (j < HD) out[j] = H[(size_t)(N_NODES - 1) * HD + j];
}

// ---------------------------------------------------------------------------
static const int lvlLo[9] = {0, 10923, 15019, 16043, 16299, 16363, 16379, 16383, 16384};
static const int lvlN[8]  = {10923, 4096, 1024, 256, 64, 16, 4, 1};

extern "C" void kernel_launch(void* const* d_in, const int* in_sizes, int n_in,
                              void* d_out, int out_size, void* d_ws, size_t ws_size,
                              hipStream_t stream)
{
    const float* x     = (const float*)d_in[0];
    const int*   cidx  = (const int*)  d_in[1];
    const int*   cdep  = (const int*)  d_in[2];
    const float* mh    = (const float*)d_in[3];
    const float* me    = (const float*)d_in[4];
    const float* demb  = (const float*)d_in[5];
    const float* iux_w = (const float*)d_in[6];
    const float* iux_b = (const float*)d_in[7];
    const float* iuh_w = (const float*)d_in[8];
    const float* iuh_b = (const float*)d_in[9];
    const float* iue_w = (const float*)d_in[10];
    const float* iue_b = (const float*)d_in[11];
    const float* fx_w  = (const float*)d_in[12];
    const float* fx_b  = (const float*)d_in[13];
    const float* fh_w  = (const float*)d_in[14];
    const float* fh_b  = (const float*)d_in[15];
    const float* fe_w  = (const float*)d_in[16];
    const float* fe_b  = (const float*)d_in[17];

    // ---- fast-path workspace layout (bytes) ----
    const size_t szHb  = (size_t)N_NODES * HD * 2;
    const size_t szXPi = (size_t)N_NODES * 1024 * 2;
    const size_t szXPf = (size_t)NINT * 512 * 2;
    const size_t szGF  = (size_t)N_NODES * HD * 2;
    const size_t szPIU = (size_t)4096 * 1024 * 2;
    const size_t szHSB = (size_t)4096 * 512 * 2;
    const size_t szXB  = (size_t)N_NODES * INP * 2;
    const size_t szWX  = (size_t)1536 * INP * 2;
    const size_t szWH  = (size_t)1536 * HD * 2;
    const size_t szIE  = (size_t)NDEP * 1024 * 4;
    const size_t szFE  = (size_t)NDEP * 512 * 4;
    const size_t szIB  = 4096, szFB = 2048;
    const size_t need = szHb + szXPi + szXPf + szGF + szPIU + szHSB
                      + szXB + szWX + szWH + szIE + szFE + szIB + szFB;

    if (ws_size >= need) {
        char* w = (char*)d_ws;
        u16*   Hb    = (u16*)w;    w += szHb;
        u16*   XPiub = (u16*)w;    w += szXPi;
        u16*   XPfb  = (u16*)w;    w += szXPf;
        u16*   GFb   = (u16*)w;    w += szGF;
        u16*   PIUa  = (u16*)w;    w += szPIU;
        u16*   HSB   = (u16*)w;    w += szHSB;
        u16*   xb    = (u16*)w;    w += szXB;
        u16*   WXb   = (u16*)w;    w += szWX;
        u16*   WHb   = (u16*)w;    w += szWH;
        float* iemb  = (float*)w;  w += szIE;
        float* femb  = (float*)w;  w += szFE;
        float* ibc   = (float*)w;  w += szIB;
        float* fbc   = (float*)w;  w += szFB;

        // 1) vectorized bf16 conversion
        hipLaunchKernelGGL(convert_vec_kernel, dim3(CV_TOT / 256), dim3(256), 0, stream,
                           x, iux_w, fx_w, iuh_w, fh_w, xb, WXb, WHb);

        // 2) XP dual GEMM + emb projection + biases
        {
            const int gx1 = N_NODES / 128, n1 = gx1 * (1024 / 128);
            const int gx2 = (NINT + 127) / 128;
            const int nG  = n1 + gx2 * (512 / 128);
            hipLaunchKernelGGL(xp_gemm_emb_kernel, dim3(nG + 385), dim3(256), 0, stream,
                               xb, WXb, XPiub, XPfb, gx1, n1, gx2, nG,
                               demb, iue_w, fe_w, iux_b, iuh_b, iue_b,
                               fx_b, fh_b, fe_b, iemb, femb, ibc, fbc);
        }

        // 3) leaves + hsum for level 1
        hipLaunchKernelGGL(fused_leaf_kernel, dim3(lvlN[1]), dim3(256), 0, stream,
                           XPiub, iemb, ibc, cidx, mh, Hb, HSB, lvlLo[1]);

        // 4..17) levels 1..7
        for (int l = 1; l < 8; ++l) {
            const int pLo = lvlLo[l - 1], pN = lvlN[l - 1];
            const int lo  = lvlLo[l],     n  = lvlN[l];
            const int gx1 = (pN + 127) / 128, n1 = gx1 * (512 / 128);
            const int gx2 = (n + 127) / 128,  n2 = gx2 * (1024 / 128);
            hipLaunchKernelGGL(gemm_bf16_dual_kernel, dim3(n1 + n2), dim3(256), 0, stream,
                               Hb + (size_t)pLo * HD, HD, WHb + (size_t)1024 * HD, HD,
                               GFb + (size_t)pLo * HD, HD, pN, HD, gx1, n1,
                               HSB, HD, WHb, HD, PIUa, 1024, n, HD, gx2);
            const int isRoot = (l == 7);
            const int gridC  = isRoot ? 1 : lvlN[l + 1];
            const int loNext = isRoot ? 0 : lvlLo[l + 1];
            hipLaunchKernelGGL(fused_combine_kernel, dim3(gridC), dim3(256), 0, stream,
                               XPiub, XPfb, PIUa, GFb, cidx, cdep, mh, me,
                               iemb, femb, ibc, fbc, Hb, HSB,
                               lo, loNext, isRoot, (float*)d_out);
        }
        return;
    }

    // ---- fallback: fused fp32 path (~34 MB ws) ----
    float* ws   = (float*)d_ws;
    float* H    = ws;
    float* iembF = H + (size_t)N_NODES * HD;
    float* fembF = iembF + (size_t)NDEP * 1024;
    float* ibcF  = fembF + (size_t)NDEP * HD;
    float* fbcF  = ibcF + 1024;

    hipLaunchKernelGGL(emb_setup_kernel, dim3(NDEP), dim3(256), 0, stream,
                       demb, iue_w, fe_w, iux_b, iuh_b, iue_b, fx_b, fh_b, fe_b,
                       iembF, fembF, ibcF, fbcF);
    for (int l = 0; l < 8; ++l) {
        dim3 grid((lvlN[l] + LM - 1) / LM, HD / LCOL);
        hipLaunchKernelGGL(level_kernel, grid, dim3(256), 0, stream,
                           x, cidx, cdep, mh, me, iux_w, iuh_w, fx_w, fh_w,
                           iembF, fembF, ibcF, fbcF, H, lvlLo[l], lvlLo[l] + lvlN[l]);
    }
    hipLaunchKernelGGL(copy_out_kernel, dim3(2), dim3(256), 0, stream, H, (float*)d_out);
}

// Round 11
// 239.160 us; speedup vs baseline: 4.2857x; 1.0284x over previous
//
#include <hip/hip_runtime.h>
#include <cstddef>

#define N_NODES 16384
#define HD      512
#define INDIM   300
#define INP     320
#define NDEP    48
#define NLEAF   10923
#define NINT    5461
#define KT      32
#define LM      16
#define LCOL    128
#define TILE_E  8192   // 128*64 u16 elems per LDS buffer half

typedef unsigned int u32;
typedef unsigned short u16;
typedef __attribute__((ext_vector_type(8))) short short8;
typedef __attribute__((ext_vector_type(4))) float f32x4;

typedef __attribute__((address_space(1))) const u32 as1_u32;
typedef __attribute__((address_space(3))) u32 as3_u32;

__device__ __forceinline__ float sigmoidf_(float v) {
    return 1.f / (1.f + __expf(-v));
}
__device__ __forceinline__ float tanhf_(float v) {
    v = fminf(15.f, fmaxf(-15.f, v));
    const float e = __expf(2.f * v);
    return (e - 1.f) / (e + 1.f);
}
__device__ __forceinline__ u16 f2bf(float f) {
    u32 u = __float_as_uint(f);
    u32 r = (u + 0x7fffu + ((u >> 16) & 1u)) >> 16;
    return (u16)r;
}
__device__ __forceinline__ float b2f(u16 v) {
    return __uint_as_float((u32)v << 16);
}
__device__ __forceinline__ u32 pack2(float a, float b) {
    return (u32)f2bf(a) | ((u32)f2bf(b) << 16);
}

// ---------------------------------------------------------------------------
// vectorized fp32->bf16 convert (rows 1200B = 75x16B => float4 clean)
// ---------------------------------------------------------------------------
#define RA  (N_NODES * 75)
#define RB  (N_NODES * 10)
#define RC1 (1536 * 75)
#define RC2 (1536 * 10)
#define RD  (1536 * 128)
#define CV_TOT (RA + RB + RC1 + RC2 + RD)

__global__ __launch_bounds__(256)
void convert_vec_kernel(const float* __restrict__ x,
                        const float* __restrict__ iux_w, const float* __restrict__ fx_w,
                        const float* __restrict__ iuh_w, const float* __restrict__ fh_w,
                        u16* __restrict__ xb, u16* __restrict__ WXb, u16* __restrict__ WHb)
{
    int idx = blockIdx.x * 256 + threadIdx.x;
    if (idx < RA) {
        const int r = idx / 75, k4 = idx - r * 75;
        const float4 v = *reinterpret_cast<const float4*>(x + (size_t)r * INDIM + k4 * 4);
        *reinterpret_cast<uint2*>(&xb[(size_t)r * INP + k4 * 4]) =
            make_uint2(pack2(v.x, v.y), pack2(v.z, v.w));
        return;
    }
    idx -= RA;
    if (idx < RB) {
        const int r = idx / 10, j = idx - r * 10;
        reinterpret_cast<u32*>(xb)[(size_t)r * 160 + 150 + j] = 0u;
        return;
    }
    idx -= RB;
    if (idx < RC1) {
        const int r = idx / 75, k4 = idx - r * 75;
        const float* src = (r < 1024) ? (iux_w + (size_t)r * INDIM)
                                      : (fx_w + (size_t)(r - 1024) * INDIM);
        const float4 v = *reinterpret_cast<const float4*>(src + k4 * 4);
        *reinterpret_cast<uint2*>(&WXb[(size_t)r * INP + k4 * 4]) =
            make_uint2(pack2(v.x, v.y), pack2(v.z, v.w));
        return;
    }
    idx -= RC1;
    if (idx < RC2) {
        const int r = idx / 10, j = idx - r * 10;
        reinterpret_cast<u32*>(WXb)[(size_t)r * 160 + 150 + j] = 0u;
        return;
    }
    idx -= RC2;
    {
        const int r = idx >> 7, k4 = idx & 127;
        const float* src = (r < 1024) ? (iuh_w + (size_t)r * HD)
                                      : (fh_w + (size_t)(r - 1024) * HD);
        const float4 v = *reinterpret_cast<const float4*>(src + k4 * 4);
        *reinterpret_cast<uint2*>(&WHb[(size_t)r * HD + k4 * 4]) =
            make_uint2(pack2(v.x, v.y), pack2(v.z, v.w));
    }
}

// ---------------------------------------------------------------------------
// bf16 MFMA GEMM body, DOUBLE-BUFFERED: C[M][N](bf16) = A[M][K] @ B[N][K]^T
// 128x128 tile, BK=64, 4 waves (2x2), 16x16x32 MFMA, global_load_lds(16B),
// XOR chunk-swizzle. T3 issue-early: stage(k+1) issued before compute(k),
// one barrier per K-step => HBM latency overlaps the MFMA phase.
// As/Bs each hold TWO 128x64 halves (16KB x2). Requires K%64==0, N%128==0.
// ---------------------------------------------------------------------------
__device__ __forceinline__
void gemm_body(u16* As, u16* Bs,
               const u16* __restrict__ A, int lda,
               const u16* __restrict__ B, int ldb,
               u16* __restrict__ C, int ldc,
               int M, int K, int bx, int by)
{
    const int tid  = threadIdx.x;
    const int lane = tid & 63;
    const int wave = tid >> 6;
    const int mBlk = bx * 128;
    const int nBlk = by * 128;

    const int wr = (wave >> 1) * 64;
    const int wc = (wave & 1) * 64;
    const int fr = lane & 15;
    const int kg = lane >> 4;

    f32x4 acc[4][4];
    #pragma unroll
    for (int i = 0; i < 4; ++i)
        #pragma unroll
        for (int j = 0; j < 4; ++j) acc[i][j] = (f32x4){0.f, 0.f, 0.f, 0.f};

    int offA[4], offB[4];
    #pragma unroll
    for (int it = 0; it < 4; ++it) {
        const int s   = it * 256 + tid;
        const int row = s >> 3, c = s & 7;
        const int cs  = c ^ (row & 7);
        int ga = mBlk + row; if (ga > M - 1) ga = M - 1;
        offA[it] = ga * lda + cs * 8;
        offB[it] = (nBlk + row) * ldb + cs * 8;
    }

    // prologue: stage k0=0 into buffer 0
    #pragma unroll
    for (int it = 0; it < 4; ++it) {
        const int ldsOff = (it * 256 + wave * 64) * 8;
        __builtin_amdgcn_global_load_lds((as1_u32*)(A + offA[it]),
                                         (as3_u32*)(&As[ldsOff]), 16, 0, 0);
        __builtin_amdgcn_global_load_lds((as1_u32*)(B + offB[it]),
                                         (as3_u32*)(&Bs[ldsOff]), 16, 0, 0);
    }
    __syncthreads();

    int cur = 0;
    for (int k0 = 0; k0 < K; k0 += 64) {
        const int nxt = cur ^ 1;
        // issue next-tile stage EARLY (in flight during compute below)
        if (k0 + 64 < K) {
            #pragma unroll
            for (int it = 0; it < 4; ++it) {
                const int ldsOff = nxt * TILE_E + (it * 256 + wave * 64) * 8;
                __builtin_amdgcn_global_load_lds((as1_u32*)(A + offA[it] + k0 + 64),
                                                 (as3_u32*)(&As[ldsOff]), 16, 0, 0);
                __builtin_amdgcn_global_load_lds((as1_u32*)(B + offB[it] + k0 + 64),
                                                 (as3_u32*)(&Bs[ldsOff]), 16, 0, 0);
            }
        }
        const u16* Ac = As + cur * TILE_E;
        const u16* Bc = Bs + cur * TILE_E;
        #pragma unroll
        for (int half = 0; half < 2; ++half) {
            const int ckb = half * 4 + kg;
            short8 af[4], bf[4];
            #pragma unroll
            for (int f = 0; f < 4; ++f) {
                const int ar = wr + f * 16 + fr;
                af[f] = *(const short8*)&Ac[ar * 64 + ((ckb ^ (ar & 7)) * 8)];
                const int br = wc + f * 16 + fr;
                bf[f] = *(const short8*)&Bc[br * 64 + ((ckb ^ (br & 7)) * 8)];
            }
            #pragma unroll
            for (int mi = 0; mi < 4; ++mi)
                #pragma unroll
                for (int ni = 0; ni < 4; ++ni)
                    acc[mi][ni] = __builtin_amdgcn_mfma_f32_16x16x32_bf16(
                                      af[mi], bf[ni], acc[mi][ni], 0, 0, 0);
        }
        __syncthreads();   // drains stage(k+1) (had full compute phase in flight)
        cur = nxt;
    }

    #pragma unroll
    for (int mi = 0; mi < 4; ++mi) {
        const int r0 = mBlk + wr + mi * 16 + kg * 4;
        #pragma unroll
        for (int v = 0; v < 4; ++v) {
            const int r = r0 + v;
            if (r >= M) continue;
            u16* crow = C + (size_t)r * ldc + nBlk + wc + fr;
            #pragma unroll
            for (int ni = 0; ni < 4; ++ni)
                crow[ni * 16] = f2bf(acc[mi][ni][v]);
        }
    }
}

// ---------------------------------------------------------------------------
// XP dual GEMM + emb projection + biases in ONE dispatch.
// emb blocks FIRST in the flat index so they overlap the MFMA blocks
// instead of trailing as a low-occupancy tail.
// ---------------------------------------------------------------------------
__global__ __launch_bounds__(256, 2)
void xp_gemm_emb_kernel(const u16* __restrict__ xb, const u16* __restrict__ WXb,
                        u16* __restrict__ XPiub, u16* __restrict__ XPfb,
                        int gx1, int n1, int gx2, int nG,
                        const float* __restrict__ demb,
                        const float* __restrict__ iue_w, const float* __restrict__ fe_w,
                        const float* __restrict__ iux_b, const float* __restrict__ iuh_b,
                        const float* __restrict__ iue_b, const float* __restrict__ fx_b,
                        const float* __restrict__ fh_b, const float* __restrict__ fe_b,
                        float* __restrict__ iemb, float* __restrict__ femb,
                        float* __restrict__ ibc, float* __restrict__ fbc)
{
    __shared__ u16 As[2 * TILE_E];
    __shared__ u16 Bs[2 * TILE_E];
    const int flat = blockIdx.x;
    if (flat >= 385) {
        const int g = flat - 385;
        if (g < n1) {
            gemm_body(As, Bs, xb, INP, WXb, INP, XPiub, 1024, N_NODES, INP,
                      g % gx1, g / gx1);
        } else {
            const int f2 = g - n1;
            gemm_body(As, Bs, xb + (size_t)NLEAF * INP, INP,
                      WXb + (size_t)1024 * INP, INP, XPfb, 512, NINT, INP,
                      f2 % gx2, f2 / gx2);
        }
        return;
    }
    const int bo  = flat;                 // [0, 385)
    const int tid = threadIdx.x;
    if (bo == 384) {
        for (int o = tid; o < 1024; o += 256) ibc[o] = iux_b[o] + iuh_b[o] + iue_b[o];
        for (int o = tid; o < 512;  o += 256) fbc[o] = fx_b[o] + fh_b[o] + fe_b[o];
        return;
    }
    const int wave = tid >> 6;
    const int d    = tid & 63;
    const bool isI = (bo < 256);
    const int o    = (isI ? bo : bo - 256) * 4 + wave;
    if (d >= NDEP) return;
    const float* wrow = isI ? (iue_w + (size_t)o * HD) : (fe_w + (size_t)o * HD);
    const float* drow = demb + (size_t)d * HD;

    float4 a0 = make_float4(0.f, 0.f, 0.f, 0.f);
    float4 a1 = make_float4(0.f, 0.f, 0.f, 0.f);
    for (int k = 0; k < HD; k += 8) {
        const float4 wv0 = *reinterpret_cast<const float4*>(wrow + k);
        const float4 wv1 = *reinterpret_cast<const float4*>(wrow + k + 4);
        const float4 dv0 = *reinterpret_cast<const float4*>(drow + k);
        const float4 dv1 = *reinterpret_cast<const float4*>(drow + k + 4);
        a0.x = fmaf(dv0.x, wv0.x, a0.x); a0.y = fmaf(dv0.y, wv0.y, a0.y);
        a0.z = fmaf(dv0.z, wv0.z, a0.z); a0.w = fmaf(dv0.w, wv0.w, a0.w);
        a1.x = fmaf(dv1.x, wv1.x, a1.x); a1.y = fmaf(dv1.y, wv1.y, a1.y);
        a1.z = fmaf(dv1.z, wv1.z, a1.z); a1.w = fmaf(dv1.w, wv1.w, a1.w);
    }
    const float s = ((a0.x + a0.y) + (a0.z + a0.w)) + ((a1.x + a1.y) + (a1.z + a1.w));
    if (isI) iemb[(size_t)d * 1024 + o] = s;
    else     femb[(size_t)d * 512  + o] = s;
}

// Two GEMM jobs in one dispatch (flat 1-D grid split) — level loop.
__global__ __launch_bounds__(256, 2)
void gemm_bf16_dual_kernel(const u16* __restrict__ A1, int lda1,
                           const u16* __restrict__ B1, int ldb1,
                           u16* __restrict__ C1, int ldc1, int M1, int K1,
                           int gx1, int n1,
                           const u16* __restrict__ A2, int lda2,
                           const u16* __restrict__ B2, int ldb2,
                           u16* __restrict__ C2, int ldc2, int M2, int K2,
                           int gx2)
{
    __shared__ u16 As[2 * TILE_E];
    __shared__ u16 Bs[2 * TILE_E];
    const int flat = blockIdx.x;
    if (flat < n1) {
        gemm_body(As, Bs, A1, lda1, B1, ldb1, C1, ldc1, M1, K1,
                  flat % gx1, flat / gx1);
    } else {
        const int f2 = flat - n1;
        gemm_body(As, Bs, A2, lda2, B2, ldb2, C2, ldc2, M2, K2,
                  f2 % gx2, f2 / gx2);
    }
}

// ---------------------------------------------------------------------------
// fused leaf + hsum: block g owns parent p = loNext+g (level-1 node), computes
// h for its <=4 leaf children, writes Hb, and HSB[g] = sum(h).
// ---------------------------------------------------------------------------
__global__ __launch_bounds__(256)
void fused_leaf_kernel(const u16* __restrict__ XPiub,
                       const float* __restrict__ iemb, const float* __restrict__ ibc,
                       const int* __restrict__ cidx, const float* __restrict__ mh,
                       u16* __restrict__ Hb, u16* __restrict__ HSB, int loNext)
{
    const int g   = blockIdx.x;
    const int p   = loNext + g;
    const int j2  = threadIdx.x * 2;

    int ct[4]; float cm[4];
    #pragma unroll
    for (int c = 0; c < 4; ++c) { ct[c] = cidx[p * 4 + c]; cm[c] = mh[p * 4 + c]; }

    const float2 ibci = *reinterpret_cast<const float2*>(&ibc[j2]);
    const float2 ibcu = *reinterpret_cast<const float2*>(&ibc[512 + j2]);
    const float2 iei  = *reinterpret_cast<const float2*>(&iemb[j2]);
    const float2 ieu  = *reinterpret_cast<const float2*>(&iemb[512 + j2]);

    float hs0 = 0.f, hs1 = 0.f;
    #pragma unroll
    for (int c = 0; c < 4; ++c) {
        if (cm[c] == 0.f) continue;
        const int t = ct[c];
        const u32 xi = *reinterpret_cast<const u32*>(&XPiub[(size_t)t * 1024 + j2]);
        const u32 xu = *reinterpret_cast<const u32*>(&XPiub[(size_t)t * 1024 + 512 + j2]);
        const float h0 = tanhf_(sigmoidf_(b2f((u16)xi) + iei.x + ibci.x)
                                * tanhf_(b2f((u16)xu) + ieu.x + ibcu.x));
        const float h1 = tanhf_(sigmoidf_(b2f((u16)(xi >> 16)) + iei.y + ibci.y)
                                * tanhf_(b2f((u16)(xu >> 16)) + ieu.y + ibcu.y));
        *reinterpret_cast<u32*>(&Hb[(size_t)t * 512 + j2]) = pack2(h0, h1);
        hs0 += h0; hs1 += h1;
    }
    *reinterpret_cast<u32*>(&HSB[(size_t)g * 512 + j2]) = pack2(hs0, hs1);
}

// ---------------------------------------------------------------------------
// fused combine + hsum for level l: block g owns parent p = loNext+g (level
// l+1); full gate math for its <=4 level-l children; writes Hb + HSB[g].
// Child hidden states for the f-path are read from Hb (bf16).
// isRoot: grid=1, node 16383, writes d_out (f32).
// ---------------------------------------------------------------------------
__global__ __launch_bounds__(256)
void fused_combine_kernel(const u16* __restrict__ XPiub, const u16* __restrict__ XPfb,
                          const u16* __restrict__ PIUb, const u16* __restrict__ GFb,
                          const int* __restrict__ cidx, const int* __restrict__ cdep,
                          const float* __restrict__ mh, const float* __restrict__ me,
                          const float* __restrict__ iemb, const float* __restrict__ femb,
                          const float* __restrict__ ibc, const float* __restrict__ fbc,
                          u16* __restrict__ Hb, u16* __restrict__ HSB,
                          int lo, int loNext, int isRoot, float* __restrict__ outp)
{
    const int j2 = threadIdx.x * 2;

    int ct[4]; float cm[4];
    if (isRoot) {
        ct[0] = N_NODES - 1; cm[0] = 1.f;
        ct[1] = ct[2] = ct[3] = 0; cm[1] = cm[2] = cm[3] = 0.f;
    } else {
        const int p = loNext + blockIdx.x;
        #pragma unroll
        for (int c = 0; c < 4; ++c) { ct[c] = cidx[p * 4 + c]; cm[c] = mh[p * 4 + c]; }
    }

    const float2 ibci = *reinterpret_cast<const float2*>(&ibc[j2]);
    const float2 ibcu = *reinterpret_cast<const float2*>(&ibc[512 + j2]);
    const float2 fbc2 = *reinterpret_cast<const float2*>(&fbc[j2]);

    float hs0 = 0.f, hs1 = 0.f;
    #pragma unroll
    for (int c = 0; c < 4; ++c) {
        if (cm[c] == 0.f) continue;
        const int t = ct[c];

        int ci2[4], dp2[4]; float m2[4], e2[4];
        #pragma unroll
        for (int k = 0; k < 4; ++k) {
            ci2[k] = cidx[t * 4 + k]; dp2[k] = cdep[t * 4 + k];
            m2[k]  = mh[t * 4 + k];   e2[k]  = me[t * 4 + k];
        }

        float ei0 = 0.f, ei1 = 0.f, eu0 = 0.f, eu1 = 0.f;
        #pragma unroll
        for (int k = 0; k < 4; ++k) {
            if (e2[k] != 0.f) {
                const float* ie = iemb + (size_t)dp2[k] * 1024;
                const float2 a = *reinterpret_cast<const float2*>(&ie[j2]);
                const float2 b = *reinterpret_cast<const float2*>(&ie[512 + j2]);
                ei0 = fmaf(e2[k], a.x, ei0); ei1 = fmaf(e2[k], a.y, ei1);
                eu0 = fmaf(e2[k], b.x, eu0); eu1 = fmaf(e2[k], b.y, eu1);
            }
        }

        const u32 xi = *reinterpret_cast<const u32*>(&XPiub[(size_t)t * 1024 + j2]);
        const u32 xu = *reinterpret_cast<const u32*>(&XPiub[(size_t)t * 1024 + 512 + j2]);
        const u32 pi = *reinterpret_cast<const u32*>(&PIUb[(size_t)(t - lo) * 1024 + j2]);
        const u32 pu = *reinterpret_cast<const u32*>(&PIUb[(size_t)(t - lo) * 1024 + 512 + j2]);
        const u32 xf = *reinterpret_cast<const u32*>(&XPfb[(size_t)(t - NLEAF) * 512 + j2]);

        const float iu_i0 = b2f((u16)xi) + b2f((u16)pi) + ibci.x + ei0;
        const float iu_i1 = b2f((u16)(xi >> 16)) + b2f((u16)(pi >> 16)) + ibci.y + ei1;
        const float iu_u0 = b2f((u16)xu) + b2f((u16)pu) + ibcu.x + eu0;
        const float iu_u1 = b2f((u16)(xu >> 16)) + b2f((u16)(pu >> 16)) + ibcu.y + eu1;
        const float xf0 = b2f((u16)xf) + fbc2.x;
        const float xf1 = b2f((u16)(xf >> 16)) + fbc2.y;

        float fcs0 = 0.f, fcs1 = 0.f;
        #pragma unroll
        for (int k = 0; k < 4; ++k) {
            if (m2[k] != 0.f) {
                const u32 gf = *reinterpret_cast<const u32*>(&GFb[(size_t)ci2[k] * 512 + j2]);
                const u32 hb = *reinterpret_cast<const u32*>(&Hb[(size_t)ci2[k] * 512 + j2]);
                const float2 fe = *reinterpret_cast<const float2*>(&femb[(size_t)dp2[k] * 512 + j2]);
                const float fv0 = b2f((u16)gf) + xf0 + fe.x;
                const float fv1 = b2f((u16)(gf >> 16)) + xf1 + fe.y;
                fcs0 = fmaf(sigmoidf_(fv0), m2[k] * b2f((u16)hb), fcs0);
                fcs1 = fmaf(sigmoidf_(fv1), m2[k] * b2f((u16)(hb >> 16)), fcs1);
            }
        }

        const float h0 = tanhf_(fmaf(sigmoidf_(iu_i0), tanhf_(iu_u0), fcs0));
        const float h1 = tanhf_(fmaf(sigmoidf_(iu_i1), tanhf_(iu_u1), fcs1));
        *reinterpret_cast<u32*>(&Hb[(size_t)t * 512 + j2]) = pack2(h0, h1);
        hs0 += h0; hs1 += h1;
        if (isRoot) *reinterpret_cast<float2*>(&outp[j2]) = make_float2(h0, h1);
    }
    if (!isRoot)
        *reinterpret_cast<u32*>(&HSB[(size_t)blockIdx.x * 512 + j2]) = pack2(hs0, hs1);
}

// ===========================================================================
// FALLBACK (round-1 fused fp32 path, needs only ~34 MB ws)
// ===========================================================================
__global__ __launch_bounds__(256)
void emb_setup_kernel(const float* __restrict__ demb,
                      const float* __restrict__ iue_w,
                      const float* __restrict__ fe_w,
                      const float* __restrict__ iux_b,
                      const float* __restrict__ iuh_b,
                      const float* __restrict__ iue_b,
                      const float* __restrict__ fx_b,
                      const float* __restrict__ fh_b,
                      const float* __restrict__ fe_b,
                      float* __restrict__ iemb,
                      float* __restrict__ femb,
                      float* __restrict__ ibc,
                      float* __restrict__ fbc)
{
    const int d   = blockIdx.x;
    const int tid = threadIdx.x;
    __shared__ float sd[HD];
    sd[tid]       = demb[d * HD + tid];
    sd[tid + 256] = demb[d * HD + 256 + tid];
    __syncthreads();

    #pragma unroll
    for (int r = 0; r < 4; ++r) {
        const int o = r * 256 + tid;
        const float* w = iue_w + (size_t)o * HD;
        float acc = 0.f;
        for (int k = 0; k < HD; k += 4) {
            const float4 wv = *reinterpret_cast<const float4*>(w + k);
            acc += sd[k] * wv.x + sd[k + 1] * wv.y + sd[k + 2] * wv.z + sd[k + 3] * wv.w;
        }
        iemb[(size_t)d * 1024 + o] = acc;
    }
    #pragma unroll
    for (int r = 0; r < 2; ++r) {
        const int o = r * 256 + tid;
        const float* w = fe_w + (size_t)o * HD;
        float acc = 0.f;
        for (int k = 0; k < HD; k += 4) {
            const float4 wv = *reinterpret_cast<const float4*>(w + k);
            acc += sd[k] * wv.x + sd[k + 1] * wv.y + sd[k + 2] * wv.z + sd[k + 3] * wv.w;
        }
        femb[(size_t)d * HD + o] = acc;
    }
    if (d == 0) {
        #pragma unroll
        for (int r = 0; r < 4; ++r) { const int o = r * 256 + tid; ibc[o] = iux_b[o] + iuh_b[o] + iue_b[o]; }
        #pragma unroll
        for (int r = 0; r < 2; ++r) { const int o = r * 256 + tid; fbc[o] = fx_b[o] + fh_b[o] + fe_b[o]; }
    }
}

__global__ __launch_bounds__(256, 2)
void level_kernel(const float* __restrict__ x,
                  const int*   __restrict__ child_idx,
                  const int*   __restrict__ child_dep,
                  const float* __restrict__ mask_h,
                  const float* __restrict__ mask_e,
                  const float* __restrict__ iux_w,
                  const float* __restrict__ iuh_w,
                  const float* __restrict__ fx_w,
                  const float* __restrict__ fh_w,
                  const float* __restrict__ iemb,
                  const float* __restrict__ femb,
                  const float* __restrict__ ibc,
                  const float* __restrict__ fbc,
                  float* __restrict__ H,
                  int tLo, int tEnd)
{
    __shared__ __align__(16) float sA[KT][68];
    __shared__ float sWI[KT][LCOL + 1];
    __shared__ float sWU[KT][LCOL + 1];
    __shared__ float sWF[KT][LCOL + 1];
    __shared__ int   sCidx[LM][4];
    __shared__ float sMh[LM][4];
    __shared__ int   sDep[LM][4];
    __shared__ float sMe[LM][4];

    const int tid  = threadIdx.x;
    const int base = tLo + blockIdx.x * LM;
    const int j0   = blockIdx.y * LCOL;

    if (tid < LM * 4) {
        const int m = tid >> 2, c = tid & 3;
        const int t = base + m;
        const bool v = (t < tEnd);
        sCidx[m][c] = v ? child_idx[t * 4 + c] : 0;
        sMh[m][c]   = v ? mask_h[t * 4 + c]    : 0.f;
        sDep[m][c]  = v ? child_dep[t * 4 + c] : 0;
        sMe[m][c]   = v ? mask_e[t * 4 + c]    : 0.f;
    }

    const int jj = tid & 63;
    const int mg = tid >> 6;

    float acc_i[4][2], acc_u[4][2], acc_fx[4][2], acc_f[4][2][4];
    #pragma unroll
    for (int mm = 0; mm < 4; ++mm)
        #pragma unroll
        for (int c2 = 0; c2 < 2; ++c2) {
            acc_i[mm][c2] = 0.f; acc_u[mm][c2] = 0.f; acc_fx[mm][c2] = 0.f;
            #pragma unroll
            for (int c = 0; c < 4; ++c) acc_f[mm][c2][c] = 0.f;
        }

    __syncthreads();

    for (int k0 = 0; k0 < HD; k0 += KT) {
        #pragma unroll
        for (int it = 0; it < 2; ++it) {
            const int chunk = tid + it * 256;
            const int mc = chunk >> 3;
            const int kk = (chunk & 7) * 4;
            const int m = mc >> 2, c = mc & 3;
            const float mhv = sMh[m][c];
            float4 v = make_float4(0.f, 0.f, 0.f, 0.f);
            if (mhv != 0.f)
                v = *reinterpret_cast<const float4*>(H + (size_t)sCidx[m][c] * HD + k0 + kk);
            sA[kk + 0][mc] = v.x; sA[kk + 1][mc] = v.y; sA[kk + 2][mc] = v.z; sA[kk + 3][mc] = v.w;
        }
        #pragma unroll
        for (int it = 0; it < 4; ++it) {
            const int chunk = tid + it * 256;
            const int row = chunk >> 3;
            const int kk = (chunk & 7) * 4;
            const float4 vI = *reinterpret_cast<const float4*>(iuh_w + (size_t)(j0 + row) * HD + k0 + kk);
            const float4 vU = *reinterpret_cast<const float4*>(iuh_w + (size_t)(j0 + row + 512) * HD + k0 + kk);
            const float4 vF = *reinterpret_cast<const float4*>(fh_w  + (size_t)(j0 + row) * HD + k0 + kk);
            sWI[kk + 0][row] = vI.x; sWI[kk + 1][row] = vI.y; sWI[kk + 2][row] = vI.z; sWI[kk + 3][row] = vI.w;
            sWU[kk + 0][row] = vU.x; sWU[kk + 1][row] = vU.y; sWU[kk + 2][row] = vU.z; sWU[kk + 3][row] = vU.w;
            sWF[kk + 0][row] = vF.x; sWF[kk + 1][row] = vF.y; sWF[kk + 2][row] = vF.z; sWF[kk + 3][row] = vF.w;
        }
        __syncthreads();
        #pragma unroll 4
        for (int k = 0; k < KT; ++k) {
            const float wi0 = sWI[k][jj], wi1 = sWI[k][jj + 64];
            const float wu0 = sWU[k][jj], wu1 = sWU[k][jj + 64];
            const float wf0 = sWF[k][jj], wf1 = sWF[k][jj + 64];
            #pragma unroll
            for (int mm = 0; mm < 4; ++mm) {
                const int m = mg + mm * 4;
                const float4 cv = *reinterpret_cast<const float4*>(&sA[k][m * 4]);
                const float hs = (cv.x + cv.y) + (cv.z + cv.w);
                acc_i[mm][0] = fmaf(hs, wi0, acc_i[mm][0]);
                acc_i[mm][1] = fmaf(hs, wi1, acc_i[mm][1]);
                acc_u[mm][0] = fmaf(hs, wu0, acc_u[mm][0]);
                acc_u[mm][1] = fmaf(hs, wu1, acc_u[mm][1]);
                acc_f[mm][0][0] = fmaf(cv.x, wf0, acc_f[mm][0][0]);
                acc_f[mm][1][0] = fmaf(cv.x, wf1, acc_f[mm][1][0]);
                acc_f[mm][0][1] = fmaf(cv.y, wf0, acc_f[mm][0][1]);
                acc_f[mm][1][1] = fmaf(cv.y, wf1, acc_f[mm][1][1]);
                acc_f[mm][0][2] = fmaf(cv.z, wf0, acc_f[mm][0][2]);
                acc_f[mm][1][2] = fmaf(cv.z, wf1, acc_f[mm][1][2]);
                acc_f[mm][0][3] = fmaf(cv.w, wf0, acc_f[mm][0][3]);
                acc_f[mm][1][3] = fmaf(cv.w, wf1, acc_f[mm][1][3]);
            }
        }
        __syncthreads();
    }

    for (int k0 = 0; k0 < INDIM; k0 += KT) {
        if (tid < 128) {
            const int m = tid >> 3;
            const int kk = (tid & 7) * 4;
            const int t = base + m;
            float4 v = make_float4(0.f, 0.f, 0.f, 0.f);
            if (t < tEnd && (k0 + kk + 3) < INDIM)
                v = *reinterpret_cast<const float4*>(x + (size_t)t * INDIM + k0 + kk);
            sA[kk + 0][m] = v.x; sA[kk + 1][m] = v.y; sA[kk + 2][m] = v.z; sA[kk + 3][m] = v.w;
        }
        #pragma unroll
        for (int it = 0; it < 4; ++it) {
            const int chunk = tid + it * 256;
            const int row = chunk >> 3;
            const int kk = (chunk & 7) * 4;
            float4 vI = make_float4(0.f, 0.f, 0.f, 0.f), vU = vI, vF = vI;
            if ((k0 + kk + 3) < INDIM) {
                vI = *reinterpret_cast<const float4*>(iux_w + (size_t)(j0 + row) * INDIM + k0 + kk);
                vU = *reinterpret_cast<const float4*>(iux_w + (size_t)(j0 + row + 512) * INDIM + k0 + kk);
                vF = *reinterpret_cast<const float4*>(fx_w  + (size_t)(j0 + row) * INDIM + k0 + kk);
            }
            sWI[kk + 0][row] = vI.x; sWI[kk + 1][row] = vI.y; sWI[kk + 2][row] = vI.z; sWI[kk + 3][row] = vI.w;
            sWU[kk + 0][row] = vU.x; sWU[kk + 1][row] = vU.y; sWU[kk + 2][row] = vU.z; sWU[kk + 3][row] = vU.w;
            sWF[kk + 0][row] = vF.x; sWF[kk + 1][row] = vF.y; sWF[kk + 2][row] = vF.z; sWF[kk + 3][row] = vF.w;
        }
        __syncthreads();
        #pragma unroll 4
        for (int k = 0; k < KT; ++k) {
            const float wi0 = sWI[k][jj], wi1 = sWI[k][jj + 64];
            const float wu0 = sWU[k][jj], wu1 = sWU[k][jj + 64];
            const float wf0 = sWF[k][jj], wf1 = sWF[k][jj + 64];
            #pragma unroll
            for (int mm = 0; mm < 4; ++mm) {
                const float xv = sA[k][mg + mm * 4];
                acc_i[mm][0]  = fmaf(xv, wi0, acc_i[mm][0]);
                acc_i[mm][1]  = fmaf(xv, wi1, acc_i[mm][1]);
                acc_u[mm][0]  = fmaf(xv, wu0, acc_u[mm][0]);
                acc_u[mm][1]  = fmaf(xv, wu1, acc_u[mm][1]);
                acc_fx[mm][0] = fmaf(xv, wf0, acc_fx[mm][0]);
                acc_fx[mm][1] = fmaf(xv, wf1, acc_fx[mm][1]);
            }
        }
        __syncthreads();
    }

    #pragma unroll
    for (int mm = 0; mm < 4; ++mm) {
        const int m = mg + mm * 4;
        const int t = base + m;
        if (t >= tEnd) continue;
        #pragma unroll
        for (int c2 = 0; c2 < 2; ++c2) {
            const int j = j0 + c2 * 64 + jj;
            float emb_i = 0.f, emb_u = 0.f;
            #pragma unroll
            for (int c = 0; c < 4; ++c) {
                const float mev = sMe[m][c];
                if (mev != 0.f) {
                    const float* ie = iemb + (size_t)sDep[m][c] * 1024;
                    emb_i = fmaf(mev, ie[j], emb_i);
                    emb_u = fmaf(mev, ie[j + 512], emb_u);
                }
            }
            const float iu_i = acc_i[mm][c2] + ibc[j] + emb_i;
            const float iu_u = acc_u[mm][c2] + ibc[j + 512] + emb_u;
            const float ig = sigmoidf_(iu_i);
            const float uu = tanhf_(iu_u);
            float fcs = 0.f;
            #pragma unroll
            for (int c = 0; c < 4; ++c) {
                const float mhv = sMh[m][c];
                if (mhv != 0.f) {
                    const float fv = acc_f[mm][c2][c] + acc_fx[mm][c2] + fbc[j]
                                   + femb[(size_t)sDep[m][c] * HD + j];
                    const float fg = sigmoidf_(fv);
                    const float chj = H[(size_t)sCidx[m][c] * HD + j] * mhv;
                    fcs = fmaf(fg, chj, fcs);
                }
            }
            H[(size_t)t * HD + j] = tanhf_(fmaf(ig, uu, fcs));
        }
    }
}

__global__ void copy_out_kernel(const float* __restrict__ H, float* __restrict__ out) {
    const int j = blockIdx.x * 256 + threadIdx.x;
    if (j < HD) out[j] = H[(size_t)(N_NODES - 1) * HD + j];
}

// ---------------------------------------------------------------------------
static const int lvlLo[9] = {0, 10923, 15019, 16043, 16299, 16363, 16379, 16383, 16384};
static const int lvlN[8]  = {10923, 4096, 1024, 256, 64, 16, 4, 1};

extern "C" void kernel_launch(void* const* d_in, const int* in_sizes, int n_in,
                              void* d_out, int out_size, void* d_ws, size_t ws_size,
                              hipStream_t stream)
{
    const float* x     = (const float*)d_in[0];
    const int*   cidx  = (const int*)  d_in[1];
    const int*   cdep  = (const int*)  d_in[2];
    const float* mh    = (const float*)d_in[3];
    const float* me    = (const float*)d_in[4];
    const float* demb  = (const float*)d_in[5];
    const float* iux_w = (const float*)d_in[6];
    const float* iux_b = (const float*)d_in[7];
    const float* iuh_w = (const float*)d_in[8];
    const float* iuh_b = (const float*)d_in[9];
    const float* iue_w = (const float*)d_in[10];
    const float* iue_b = (const float*)d_in[11];
    const float* fx_w  = (const float*)d_in[12];
    const float* fx_b  = (const float*)d_in[13];
    const float* fh_w  = (const float*)d_in[14];
    const float* fh_b  = (const float*)d_in[15];
    const float* fe_w  = (const float*)d_in[16];
    const float* fe_b  = (const float*)d_in[17];

    // ---- fast-path workspace layout (bytes) ----
    const size_t szHb  = (size_t)N_NODES * HD * 2;
    const size_t szXPi = (size_t)N_NODES * 1024 * 2;
    const size_t szXPf = (size_t)NINT * 512 * 2;
    const size_t szGF  = (size_t)N_NODES * HD * 2;
    const size_t szPIU = (size_t)4096 * 1024 * 2;
    const size_t szHSB = (size_t)4096 * 512 * 2;
    const size_t szXB  = (size_t)N_NODES * INP * 2;
    const size_t szWX  = (size_t)1536 * INP * 2;
    const size_t szWH  = (size_t)1536 * HD * 2;
    const size_t szIE  = (size_t)NDEP * 1024 * 4;
    const size_t szFE  = (size_t)NDEP * 512 * 4;
    const size_t szIB  = 4096, szFB = 2048;
    const size_t need = szHb + szXPi + szXPf + szGF + szPIU + szHSB
                      + szXB + szWX + szWH + szIE + szFE + szIB + szFB;

    if (ws_size >= need) {
        char* w = (char*)d_ws;
        u16*   Hb    = (u16*)w;    w += szHb;
        u16*   XPiub = (u16*)w;    w += szXPi;
        u16*   XPfb  = (u16*)w;    w += szXPf;
        u16*   GFb   = (u16*)w;    w += szGF;
        u16*   PIUa  = (u16*)w;    w += szPIU;
        u16*   HSB   = (u16*)w;    w += szHSB;
        u16*   xb    = (u16*)w;    w += szXB;
        u16*   WXb   = (u16*)w;    w += szWX;
        u16*   WHb   = (u16*)w;    w += szWH;
        float* iemb  = (float*)w;  w += szIE;
        float* femb  = (float*)w;  w += szFE;
        float* ibc   = (float*)w;  w += szIB;
        float* fbc   = (float*)w;  w += szFB;

        // 1) vectorized bf16 conversion
        hipLaunchKernelGGL(convert_vec_kernel, dim3(CV_TOT / 256), dim3(256), 0, stream,
                           x, iux_w, fx_w, iuh_w, fh_w, xb, WXb, WHb);

        // 2) XP dual GEMM + emb projection + biases (emb blocks first)
        {
            const int gx1 = N_NODES / 128, n1 = gx1 * (1024 / 128);
            const int gx2 = (NINT + 127) / 128;
            const int nG  = n1 + gx2 * (512 / 128);
            hipLaunchKernelGGL(xp_gemm_emb_kernel, dim3(nG + 385), dim3(256), 0, stream,
                               xb, WXb, XPiub, XPfb, gx1, n1, gx2, nG,
                               demb, iue_w, fe_w, iux_b, iuh_b, iue_b,
                               fx_b, fh_b, fe_b, iemb, femb, ibc, fbc);
        }

        // 3) leaves + hsum for level 1
        hipLaunchKernelGGL(fused_leaf_kernel, dim3(lvlN[1]), dim3(256), 0, stream,
                           XPiub, iemb, ibc, cidx, mh, Hb, HSB, lvlLo[1]);

        // 4..17) levels 1..7
        for (int l = 1; l < 8; ++l) {
            const int pLo = lvlLo[l - 1], pN = lvlN[l - 1];
            const int lo  = lvlLo[l],     n  = lvlN[l];
            const int gx1 = (pN + 127) / 128, n1 = gx1 * (512 / 128);
            const int gx2 = (n + 127) / 128,  n2 = gx2 * (1024 / 128);
            hipLaunchKernelGGL(gemm_bf16_dual_kernel, dim3(n1 + n2), dim3(256), 0, stream,
                               Hb + (size_t)pLo * HD, HD, WHb + (size_t)1024 * HD, HD,
                               GFb + (size_t)pLo * HD, HD, pN, HD, gx1, n1,
                               HSB, HD, WHb, HD, PIUa, 1024, n, HD, gx2);
            const int isRoot = (l == 7);
            const int gridC  = isRoot ? 1 : lvlN[l + 1];
            const int loNext = isRoot ? 0 : lvlLo[l + 1];
            hipLaunchKernelGGL(fused_combine_kernel, dim3(gridC), dim3(256), 0, stream,
                               XPiub, XPfb, PIUa, GFb, cidx, cdep, mh, me,
                               iemb, femb, ibc, fbc, Hb, HSB,
                               lo, loNext, isRoot, (float*)d_out);
        }
        return;
    }

    // ---- fallback: fused fp32 path (~34 MB ws) ----
    float* ws   = (float*)d_ws;
    float* H    = ws;
    float* iembF = H + (size_t)N_NODES * HD;
    float* fembF = iembF + (size_t)NDEP * 1024;
    float* ibcF  = fembF + (size_t)NDEP * HD;
    float* fbcF  = ibcF + 1024;

    hipLaunchKernelGGL(emb_setup_kernel, dim3(NDEP), dim3(256), 0, stream,
                       demb, iue_w, fe_w, iux_b, iuh_b, iue_b, fx_b, fh_b, fe_b,
                       iembF, fembF, ibcF, fbcF);
    for (int l = 0; l < 8; ++l) {
        dim3 grid((lvlN[l] + LM - 1) / LM, HD / LCOL);
        hipLaunchKernelGGL(level_kernel, grid, dim3(256), 0, stream,
                           x, cidx, cdep, mh, me, iux_w, iuh_w, fx_w, fh_w,
                           iembF, fembF, ibcF, fbcF, H, lvlLo[l], lvlLo[l] + lvlN[l]);
    }
    hipLaunchKernelGGL(copy_out_kernel, dim3(2), dim3(256), 0, stream, H, (float*)d_out);
}